// Round 5
// baseline (1201.190 us; speedup 1.0000x reference)
//
#include <hip/hip_runtime.h>

// Problem constants (match reference)
#define N_NODES 100000
#define N_EDGES 1600000
#define CCH     128
#define BG      512
#define NHID    512
#define NOUT    256
#define BN_EPS  1e-5f

typedef __attribute__((ext_vector_type(8))) short s16x8;
typedef __attribute__((ext_vector_type(4))) float f32x4;

static __device__ __forceinline__ float leaky(float x) { return x > 0.f ? x : 0.2f * x; }
// bf16 round-to-nearest-even, returns low 16 bits
static __device__ __forceinline__ uint32_t bfr16(float x) {
  uint32_t u = __float_as_uint(x);
  u += 0x7fffu + ((u >> 16) & 1u);
  return u >> 16;
}
static __device__ __forceinline__ uint32_t pack2(float a, float b) {
  return bfr16(a) | (bfr16(b) << 16);
}
static __device__ __forceinline__ float blo(uint32_t u) { return __uint_as_float(u << 16); }
static __device__ __forceinline__ float bhi(uint32_t u) { return __uint_as_float(u & 0xffff0000u); }

// ---------------- graph prep ----------------
__global__ void hist_kernel(const int* __restrict__ dst, int* __restrict__ indeg) {
  int e = blockIdx.x * 256 + threadIdx.x;
  if (e < N_EDGES) atomicAdd(&indeg[dst[e]], 1);
}

__global__ __launch_bounds__(256) void scan_chunks(const int* __restrict__ indeg,
                                                   int* __restrict__ rowstart,
                                                   int* __restrict__ chunksum) {
  int tid = threadIdx.x;
  int base = blockIdx.x * 1024 + tid * 4;
  int4 v;
  if (base + 3 < N_NODES) {
    v = *(const int4*)(indeg + base);
  } else {
    v.x = (base + 0 < N_NODES) ? indeg[base + 0] : 0;
    v.y = (base + 1 < N_NODES) ? indeg[base + 1] : 0;
    v.z = (base + 2 < N_NODES) ? indeg[base + 2] : 0;
    v.w = (base + 3 < N_NODES) ? indeg[base + 3] : 0;
  }
  int s = v.x + v.y + v.z + v.w;
  __shared__ int ss[256];
  ss[tid] = s;
  __syncthreads();
  for (int off = 1; off < 256; off <<= 1) {
    int t = (tid >= off) ? ss[tid - off] : 0;
    __syncthreads();
    ss[tid] += t;
    __syncthreads();
  }
  int excl = ss[tid] - s;
  if (base + 0 < N_NODES) rowstart[base + 0] = excl;
  if (base + 1 < N_NODES) rowstart[base + 1] = excl + v.x;
  if (base + 2 < N_NODES) rowstart[base + 2] = excl + v.x + v.y;
  if (base + 3 < N_NODES) rowstart[base + 3] = excl + v.x + v.y + v.z;
  if (tid == 255) chunksum[blockIdx.x] = ss[255];
}

__global__ void scan_sums(int* __restrict__ chunksum, int nch) {
  __shared__ int ss[128];
  int tid = threadIdx.x;
  int v = (tid < nch) ? chunksum[tid] : 0;
  ss[tid] = v;
  __syncthreads();
  for (int off = 1; off < 128; off <<= 1) {
    int t = (tid >= off) ? ss[tid - off] : 0;
    __syncthreads();
    ss[tid] += t;
    __syncthreads();
  }
  if (tid < nch) chunksum[tid] = ss[tid] - v;  // exclusive
}

__global__ void scan_add(int* __restrict__ rowstart, const int* __restrict__ chunksum) {
  int i = blockIdx.x * 256 + threadIdx.x;
  if (i < N_NODES)      rowstart[i] += chunksum[i >> 10];
  else if (i == N_NODES) rowstart[N_NODES] = N_EDGES;
}

__global__ void compute_dinv(const int* __restrict__ indeg, float* __restrict__ dinv) {
  int i = blockIdx.x * 256 + threadIdx.x;
  if (i < N_NODES) dinv[i] = rsqrtf((float)(indeg[i] + 1));
}

__global__ void scatter_edges(const int* __restrict__ src, const int* __restrict__ dst,
                              const int* __restrict__ rowstart, int* __restrict__ cursor,
                              const float* __restrict__ dinv, int2* __restrict__ csr_sw) {
  int e = blockIdx.x * 256 + threadIdx.x;
  if (e < N_EDGES) {
    int d = dst[e];
    int s = src[e];
    int p = rowstart[d] + atomicAdd(&cursor[d], 1);
    float w = dinv[s] * dinv[d];
    csr_sw[p] = make_int2(s, __float_as_int(w));
  }
}

// ---------------- bf16 helpers ----------------
__global__ void cast_bf16_kernel(const float2* __restrict__ x2, uint32_t* __restrict__ xb) {
  size_t idx = (size_t)blockIdx.x * 256 + threadIdx.x;
  if (idx >= (size_t)N_NODES * 64) return;
  float2 v = x2[idx];
  xb[idx] = pack2(v.x, v.y);
}

// pack W[128][128] f32 into MFMA b-frag order
__global__ void pack_w_kernel(const float* __restrict__ W, unsigned short* __restrict__ Wp) {
  int t = blockIdx.x * 256 + threadIdx.x;
  if (t >= 2048) return;
  int lane = t & 63;
  int ks = (t >> 6) & 3;
  int nt = t >> 8;
  int c = nt * 16 + (lane & 15);
  int kb = ks * 32 + (lane >> 4) * 8;
#pragma unroll
  for (int i = 0; i < 8; ++i)
    Wp[(size_t)t * 8 + i] = (unsigned short)bfr16(W[(size_t)(kb + i) * 128 + c]);
}

// ---------------- MFMA conv GEMM ----------------
__global__ __launch_bounds__(256) void gemm_mfma(const uint32_t* __restrict__ Ab,
                                                 const unsigned short* __restrict__ Wp,
                                                 uint32_t* __restrict__ Hb,
                                                 int M) {
  int wave = threadIdx.x >> 6, lane = threadIdx.x & 63;
  int row0 = blockIdx.x * 128 + wave * 32;
  const unsigned short* A16 = (const unsigned short*)Ab;

  f32x4 acc[2][8];
#pragma unroll
  for (int mt = 0; mt < 2; ++mt)
#pragma unroll
    for (int nt = 0; nt < 8; ++nt) acc[mt][nt] = (f32x4){0.f, 0.f, 0.f, 0.f};

  s16x8 a[2][4];
  int r = lane & 15, ko = (lane >> 4) * 8;
#pragma unroll
  for (int mt = 0; mt < 2; ++mt) {
    int row = row0 + mt * 16 + r;
    bool v = row < M;
    const unsigned short* ap = A16 + (size_t)row * 128 + ko;
#pragma unroll
    for (int ks = 0; ks < 4; ++ks) {
      s16x8 af = {0, 0, 0, 0, 0, 0, 0, 0};
      if (v) af = *(const s16x8*)(ap + ks * 32);
      a[mt][ks] = af;
    }
  }
#pragma unroll
  for (int ks = 0; ks < 4; ++ks) {
#pragma unroll
    for (int nt = 0; nt < 8; ++nt) {
      s16x8 b = *(const s16x8*)(Wp + ((size_t)(nt * 4 + ks) * 64 + lane) * 8);
      acc[0][nt] = __builtin_amdgcn_mfma_f32_16x16x32_bf16(a[0][ks], b, acc[0][nt], 0, 0, 0);
      acc[1][nt] = __builtin_amdgcn_mfma_f32_16x16x32_bf16(a[1][ks], b, acc[1][nt], 0, 0, 0);
    }
  }
#pragma unroll
  for (int mt = 0; mt < 2; ++mt) {
#pragma unroll
    for (int nt = 0; nt < 8; ++nt) {
#pragma unroll
      for (int reg = 0; reg < 4; ++reg) {
        float v0 = acc[mt][nt][reg];
        float v1 = __shfl_xor(v0, 1);
        int row = row0 + mt * 16 + (lane >> 4) * 4 + reg;
        int col = nt * 16 + (lane & 15);
        if (!(lane & 1) && row < M)
          Hb[(size_t)row * 64 + (col >> 1)] = pack2(v0, v1);
      }
    }
  }
}

// ---------------- unified aggregation: 2 nodes/wave, 2-deep pipelined gathers + BN stats ----
// pack.y holds the per-edge weight (GCN: dinv[s]*dinv[d]; GAT: exp(leaky(es+ed)) from gat_prep).
template <int GAT>
__global__ __launch_bounds__(256) void agg_kernel(const uint2* __restrict__ Hb2,
                                                  const int* __restrict__ rowstart,
                                                  const int2* __restrict__ pack,
                                                  const float* __restrict__ dinv,
                                                  const float* __restrict__ wselfa,
                                                  const float* __restrict__ winv,
                                                  float4* __restrict__ agg4,
                                                  float* __restrict__ stats) {
  int tid = threadIdx.x;
  int lane = tid & 63;
  int hl = lane & 31;
  int half = lane >> 5;
  int gw = (blockIdx.x * 256 + tid) >> 6;
  int nw = (gridDim.x * 256) >> 6;
  float s0 = 0, s1 = 0, s2 = 0, s3 = 0, q0 = 0, q1 = 0, q2 = 0, q3 = 0;
  for (int pi = gw; pi < N_NODES / 2; pi += nw) {
    int n = 2 * pi + half;
    int e0 = rowstart[n], e1 = rowstart[n + 1];
    int len = e1 - e0;
    int G = (len + 3) >> 2;
    int Gmax = max(G, __shfl_xor(G, 32));
    int ecl = (len > 0) ? (e1 - 1) : 0;
    float selfw, fscale;
    if (GAT) { selfw = wselfa[n]; fscale = winv[n]; }
    else     { float di = dinv[n]; selfw = di * di; fscale = 1.f; }
    uint2 hs = Hb2[(size_t)n * 32 + hl];
    float c0 = blo(hs.x) * selfw, c1 = bhi(hs.x) * selfw;
    float c2 = blo(hs.y) * selfw, c3 = bhi(hs.y) * selfw;

    if (Gmax > 0) {
      // group-g data (rows arrived one iteration earlier)
      uint2 rA0, rA1, rA2, rA3;
      float wA0, wA1, wA2, wA3;
      // group-(g+1) indices/weights
      int iB0, iB1, iB2, iB3;
      float wB0 = 0, wB1 = 0, wB2 = 0, wB3 = 0;
      iB0 = iB1 = iB2 = iB3 = 0;
      {
        int e = e0;
        int2 pa = pack[e < e1 ? e : ecl];
        int2 pb = pack[e + 1 < e1 ? e + 1 : ecl];
        int2 pc = pack[e + 2 < e1 ? e + 2 : ecl];
        int2 pd = pack[e + 3 < e1 ? e + 3 : ecl];
        wA0 = (e < e1) ? __int_as_float(pa.y) : 0.f;
        wA1 = (e + 1 < e1) ? __int_as_float(pb.y) : 0.f;
        wA2 = (e + 2 < e1) ? __int_as_float(pc.y) : 0.f;
        wA3 = (e + 3 < e1) ? __int_as_float(pd.y) : 0.f;
        rA0 = Hb2[(size_t)pa.x * 32 + hl];
        rA1 = Hb2[(size_t)pb.x * 32 + hl];
        rA2 = Hb2[(size_t)pc.x * 32 + hl];
        rA3 = Hb2[(size_t)pd.x * 32 + hl];
      }
      if (Gmax > 1) {
        int e = e0 + 4;
        int2 pa = pack[e < e1 ? e : ecl];
        int2 pb = pack[e + 1 < e1 ? e + 1 : ecl];
        int2 pc = pack[e + 2 < e1 ? e + 2 : ecl];
        int2 pd = pack[e + 3 < e1 ? e + 3 : ecl];
        iB0 = pa.x; wB0 = (e < e1) ? __int_as_float(pa.y) : 0.f;
        iB1 = pb.x; wB1 = (e + 1 < e1) ? __int_as_float(pb.y) : 0.f;
        iB2 = pc.x; wB2 = (e + 2 < e1) ? __int_as_float(pc.y) : 0.f;
        iB3 = pd.x; wB3 = (e + 3 < e1) ? __int_as_float(pd.y) : 0.f;
      }
      for (int g = 0; g < Gmax; ++g) {
        uint2 rB0, rB1, rB2, rB3;
        int nI0, nI1, nI2, nI3;
        float nw0, nw1, nw2, nw3;
        if (g + 1 < Gmax) {               // uniform branch
          rB0 = Hb2[(size_t)iB0 * 32 + hl];
          rB1 = Hb2[(size_t)iB1 * 32 + hl];
          rB2 = Hb2[(size_t)iB2 * 32 + hl];
          rB3 = Hb2[(size_t)iB3 * 32 + hl];
        }
        if (g + 2 < Gmax) {               // uniform branch
          int e = e0 + (g + 2) * 4;
          int2 pa = pack[e < e1 ? e : ecl];
          int2 pb = pack[e + 1 < e1 ? e + 1 : ecl];
          int2 pc = pack[e + 2 < e1 ? e + 2 : ecl];
          int2 pd = pack[e + 3 < e1 ? e + 3 : ecl];
          nI0 = pa.x; nw0 = (e < e1) ? __int_as_float(pa.y) : 0.f;
          nI1 = pb.x; nw1 = (e + 1 < e1) ? __int_as_float(pb.y) : 0.f;
          nI2 = pc.x; nw2 = (e + 2 < e1) ? __int_as_float(pc.y) : 0.f;
          nI3 = pd.x; nw3 = (e + 3 < e1) ? __int_as_float(pd.y) : 0.f;
        }
        // consume group g (rows issued last iteration)
        c0 = fmaf(blo(rA0.x), wA0, c0); c1 = fmaf(bhi(rA0.x), wA0, c1);
        c2 = fmaf(blo(rA0.y), wA0, c2); c3 = fmaf(bhi(rA0.y), wA0, c3);
        c0 = fmaf(blo(rA1.x), wA1, c0); c1 = fmaf(bhi(rA1.x), wA1, c1);
        c2 = fmaf(blo(rA1.y), wA1, c2); c3 = fmaf(bhi(rA1.y), wA1, c3);
        c0 = fmaf(blo(rA2.x), wA2, c0); c1 = fmaf(bhi(rA2.x), wA2, c1);
        c2 = fmaf(blo(rA2.y), wA2, c2); c3 = fmaf(bhi(rA2.y), wA2, c3);
        c0 = fmaf(blo(rA3.x), wA3, c0); c1 = fmaf(bhi(rA3.x), wA3, c1);
        c2 = fmaf(blo(rA3.y), wA3, c2); c3 = fmaf(bhi(rA3.y), wA3, c3);
        // rotate
        rA0 = rB0; rA1 = rB1; rA2 = rB2; rA3 = rB3;
        wA0 = wB0; wA1 = wB1; wA2 = wB2; wA3 = wB3;
        iB0 = nI0; iB1 = nI1; iB2 = nI2; iB3 = nI3;
        wB0 = nw0; wB1 = nw1; wB2 = nw2; wB3 = nw3;
      }
    }
    if (GAT) { c0 *= fscale; c1 *= fscale; c2 *= fscale; c3 *= fscale; }
    agg4[(size_t)n * 32 + hl] = make_float4(c0, c1, c2, c3);
    s0 += c0; s1 += c1; s2 += c2; s3 += c3;
    q0 += c0 * c0; q1 += c1 * c1; q2 += c2 * c2; q3 += c3 * c3;
  }
  // cross-half combine (both halves hold same channels 4hl..4hl+3)
  s0 += __shfl_xor(s0, 32); s1 += __shfl_xor(s1, 32);
  s2 += __shfl_xor(s2, 32); s3 += __shfl_xor(s3, 32);
  q0 += __shfl_xor(q0, 32); q1 += __shfl_xor(q1, 32);
  q2 += __shfl_xor(q2, 32); q3 += __shfl_xor(q3, 32);
  __shared__ float red[4][128];
  int w = tid >> 6;
  if (half == 0) {
    red[w][4 * hl + 0] = s0; red[w][4 * hl + 1] = s1;
    red[w][4 * hl + 2] = s2; red[w][4 * hl + 3] = s3;
  }
  __syncthreads();
  if (w == 0) {
    float a = red[0][2 * lane] + red[1][2 * lane] + red[2][2 * lane] + red[3][2 * lane];
    float b = red[0][2 * lane + 1] + red[1][2 * lane + 1] + red[2][2 * lane + 1] + red[3][2 * lane + 1];
    atomicAdd(&stats[2 * lane], a);
    atomicAdd(&stats[2 * lane + 1], b);
  }
  __syncthreads();
  if (half == 0) {
    red[w][4 * hl + 0] = q0; red[w][4 * hl + 1] = q1;
    red[w][4 * hl + 2] = q2; red[w][4 * hl + 3] = q3;
  }
  __syncthreads();
  if (w == 0) {
    float a = red[0][2 * lane] + red[1][2 * lane] + red[2][2 * lane] + red[3][2 * lane];
    float b = red[0][2 * lane + 1] + red[1][2 * lane + 1] + red[2][2 * lane + 1] + red[3][2 * lane + 1];
    atomicAdd(&stats[128 + 2 * lane], a);
    atomicAdd(&stats[128 + 2 * lane + 1], b);
  }
}

// ---------------- es/ed for GAT ----------------
__global__ __launch_bounds__(256) void compute_esed(const uint32_t* __restrict__ Hb,
                                                    const float* __restrict__ asrc,
                                                    const float* __restrict__ adst,
                                                    float* __restrict__ es, float* __restrict__ ed) {
  int lane = threadIdx.x & 63;
  int gwave = (blockIdx.x * 256 + threadIdx.x) >> 6;
  if (gwave >= N_NODES) return;
  float2 av = ((const float2*)asrc)[lane];
  float2 dv = ((const float2*)adst)[lane];
  uint32_t hv = Hb[(size_t)gwave * 64 + lane];
  float hx = blo(hv), hy = bhi(hv);
  float e_s = hx * av.x + hy * av.y;
  float e_d = hx * dv.x + hy * dv.y;
  for (int off = 32; off; off >>= 1) {
    e_s += __shfl_down(e_s, off);
    e_d += __shfl_down(e_d, off);
  }
  if (lane == 0) { es[gwave] = e_s; ed[gwave] = e_d; }
}

// per-node: overwrite pack.y with w = exp(leaky(es[src]+ed[n])), write wself & 1/(sum+1e-16)
__global__ void gat_prep_node(int2* __restrict__ pack, const int* __restrict__ rowstart,
                              const float* __restrict__ es, const float* __restrict__ ed,
                              float* __restrict__ wselfa, float* __restrict__ winv) {
  int n = blockIdx.x * 256 + threadIdx.x;
  if (n >= N_NODES) return;
  int e0 = rowstart[n], e1 = rowstart[n + 1];
  float edi = ed[n];
  float wself = __expf(leaky(es[n] + edi));
  float s = wself;
  for (int e = e0; e < e1; ++e) {
    int sidx = pack[e].x;
    float w = __expf(leaky(es[sidx] + edi));
    pack[e].y = __float_as_int(w);
    s += w;
  }
  wselfa[n] = wself;
  winv[n] = 1.f / (s + 1e-16f);
}

// ---------------- BN(train) + ReLU + residual (bf16 x chain, in-place) ----------------
__global__ void bn_relu_res(const float4* __restrict__ agg4, const float* __restrict__ stats,
                            const float* __restrict__ gamma, const float* __restrict__ beta,
                            uint2* __restrict__ xb) {
  size_t idx = (size_t)blockIdx.x * 256 + threadIdx.x;  // float4 / uint2 index
  if (idx >= (size_t)N_NODES * 32) return;
  int c = ((int)(idx & 31)) * 4;
  const float n_inv = 1.f / (float)N_NODES;
  float sc[4], bc[4];
#pragma unroll
  for (int k = 0; k < 4; ++k) {
    float m = stats[c + k] * n_inv;
    float v = stats[128 + c + k] * n_inv - m * m;
    sc[k] = gamma[c + k] * rsqrtf(v + BN_EPS);
    bc[k] = beta[c + k] - m * sc[k];
  }
  float4 a = agg4[idx];
  uint2 xi = xb[idx];
  float r0 = fmaxf(fmaf(a.x, sc[0], bc[0]), 0.f) + blo(xi.x);
  float r1 = fmaxf(fmaf(a.y, sc[1], bc[1]), 0.f) + bhi(xi.x);
  float r2 = fmaxf(fmaf(a.z, sc[2], bc[2]), 0.f) + blo(xi.y);
  float r3 = fmaxf(fmaf(a.w, sc[3], bc[3]), 0.f) + bhi(xi.y);
  xb[idx] = make_uint2(pack2(r0, r1), pack2(r2, r3));
}

// ---------------- pooling (reads bf16 x) ----------------
__global__ void graph_starts(const int* __restrict__ batch, int* __restrict__ gstart) {
  int n = blockIdx.x * 256 + threadIdx.x;
  if (n >= N_NODES) return;
  int b = batch[n];
  int bp = (n == 0) ? -1 : batch[n - 1];
  for (int g = bp + 1; g <= b; ++g) gstart[g] = n;
  if (n == N_NODES - 1) {
    for (int g = b + 1; g <= BG; ++g) gstart[g] = N_NODES;
  }
}

__global__ __launch_bounds__(256) void pool_kernel(const uint32_t* __restrict__ xb,
                                                   const int* __restrict__ gstart,
                                                   float* __restrict__ pooled) {
  int g = blockIdx.x;
  int c = threadIdx.x & 127;
  int half = threadIdx.x >> 7;
  int s = gstart[g], e = gstart[g + 1];
  float acc = 0.f;
  for (int n = s + half; n < e; n += 2) {
    uint32_t u = xb[(size_t)n * 64 + (c >> 1)];
    acc += (c & 1) ? bhi(u) : blo(u);
  }
  __shared__ float red[256];
  red[threadIdx.x] = acc;
  __syncthreads();
  if (half == 0) {
    float v = red[c] + red[128 + c];
    int cnt = e - s;
    pooled[(size_t)g * 128 + c] = v / fmaxf((float)cnt, 1.f);
  }
}

// ---------------- f32 GEMM (MLP head only) ----------------
template <int RELU, int BIAS>
__global__ __launch_bounds__(256) void gemm_f32(const float* __restrict__ A,
                                                const float* __restrict__ W,
                                                const float* __restrict__ bias,
                                                float* __restrict__ Cmat,
                                                int M, int K, int N) {
  __shared__ float As[32][128];
  __shared__ float Bs[32][128];
  int tid = threadIdx.x;
  int row0 = blockIdx.x * 128, col0 = blockIdx.y * 128;
  int tx = tid & 15, ty = tid >> 4;
  float acc[8][8];
#pragma unroll
  for (int i = 0; i < 8; ++i)
#pragma unroll
    for (int j = 0; j < 8; ++j) acc[i][j] = 0.f;

  for (int k0 = 0; k0 < K; k0 += 32) {
    {
      int r = tid >> 1;
      int kseg = (tid & 1) * 16;
      bool valid = (row0 + r) < M;
      const float* ap = A + (size_t)(row0 + r) * K + k0 + kseg;
#pragma unroll
      for (int q = 0; q < 4; ++q) {
        float4 v;
        if (valid) v = *(const float4*)(ap + q * 4);
        else { v.x = v.y = v.z = v.w = 0.f; }
        As[kseg + q * 4 + 0][r] = v.x;
        As[kseg + q * 4 + 1][r] = v.y;
        As[kseg + q * 4 + 2][r] = v.z;
        As[kseg + q * 4 + 3][r] = v.w;
      }
    }
    {
      int kk = tid >> 3;
      int seg = (tid & 7) * 16;
      const float* wp = W + (size_t)(k0 + kk) * N + col0 + seg;
#pragma unroll
      for (int q = 0; q < 4; ++q)
        *(float4*)&Bs[kk][seg + q * 4] = *(const float4*)(wp + q * 4);
    }
    __syncthreads();
#pragma unroll
    for (int kk = 0; kk < 32; ++kk) {
      float4 a0 = *(const float4*)&As[kk][ty * 4];
      float4 a1 = *(const float4*)&As[kk][64 + ty * 4];
      float4 b0 = *(const float4*)&Bs[kk][tx * 4];
      float4 b1 = *(const float4*)&Bs[kk][64 + tx * 4];
      float av[8] = {a0.x, a0.y, a0.z, a0.w, a1.x, a1.y, a1.z, a1.w};
      float bv[8] = {b0.x, b0.y, b0.z, b0.w, b1.x, b1.y, b1.z, b1.w};
#pragma unroll
      for (int i = 0; i < 8; ++i)
#pragma unroll
        for (int j = 0; j < 8; ++j) acc[i][j] = fmaf(av[i], bv[j], acc[i][j]);
    }
    __syncthreads();
  }
#pragma unroll
  for (int i = 0; i < 8; ++i) {
    int r = row0 + ((i < 4) ? (ty * 4 + i) : (64 + ty * 4 + i - 4));
    if (r >= M) continue;
#pragma unroll
    for (int j = 0; j < 8; ++j) {
      int c = col0 + ((j < 4) ? (tx * 4 + j) : (64 + tx * 4 + j - 4));
      float v = acc[i][j];
      if (BIAS) v += bias[c];
      if (RELU) v = fmaxf(v, 0.f);
      Cmat[(size_t)r * N + c] = v;
    }
  }
}

// ---------------- host launch ----------------
extern "C" void kernel_launch(void* const* d_in, const int* in_sizes, int n_in,
                              void* d_out, int out_size, void* d_ws, size_t ws_size,
                              hipStream_t stream) {
  const float* x_in  = (const float*)d_in[0];
  const int*   eidx  = (const int*)d_in[1];
  const int*   batch = (const int*)d_in[2];
  const float* W1 = (const float*)d_in[3];
  const float* g1 = (const float*)d_in[5];
  const float* be1 = (const float*)d_in[6];
  const float* W2 = (const float*)d_in[7];
  const float* g2 = (const float*)d_in[9];
  const float* be2 = (const float*)d_in[10];
  const float* W3 = (const float*)d_in[11];
  const float* g3 = (const float*)d_in[13];
  const float* be3 = (const float*)d_in[14];
  const float* Wa = (const float*)d_in[15];
  const float* asrc = (const float*)d_in[16];
  const float* adst = (const float*)d_in[17];
  const float* ga = (const float*)d_in[19];
  const float* bea = (const float*)d_in[20];
  const float* Wh1 = (const float*)d_in[21];
  const float* bh1 = (const float*)d_in[22];
  const float* Wm0 = (const float*)d_in[23];
  const float* bm0 = (const float*)d_in[24];
  const float* Wm1 = (const float*)d_in[25];
  const float* bm1 = (const float*)d_in[26];
  const float* Wo = (const float*)d_in[27];
  const float* bo = (const float*)d_in[28];

  const int* src = eidx;
  const int* dst = eidx + N_EDGES;

  char* p = (char*)d_ws;
  auto alloc = [&](size_t bytes) {
    char* r = p;
    p += (bytes + 255) & ~(size_t)255;
    return r;
  };
  uint32_t* Hb     = (uint32_t*)alloc((size_t)N_NODES * 64 * 4);   // bf16-pair h
  uint32_t* xb     = (uint32_t*)alloc((size_t)N_NODES * 64 * 4);   // bf16-pair x
  float* agg       = (float*)alloc((size_t)N_NODES * CCH * 4);
  int2*  csr_sw    = (int2*)alloc((size_t)N_EDGES * 8);
  int*   rowstart  = (int*)alloc((size_t)(N_NODES + 1) * 4);
  int*   indeg     = (int*)alloc((size_t)2 * N_NODES * 4);
  int*   cursor    = indeg + N_NODES;
  float* dinv      = (float*)alloc((size_t)N_NODES * 4);
  float* es        = (float*)alloc((size_t)N_NODES * 4);
  float* ed        = (float*)alloc((size_t)N_NODES * 4);
  float* wselfa    = (float*)alloc((size_t)N_NODES * 4);
  float* winv      = (float*)alloc((size_t)N_NODES * 4);
  int*   chunksum  = (int*)alloc(128 * 4);
  float* stats     = (float*)alloc(4 * 256 * 4);
  int*   gstart    = (int*)alloc((BG + 1) * 4);
  float* pooled    = (float*)alloc((size_t)BG * CCH * 4);
  float* m1        = (float*)alloc((size_t)BG * NHID * 4);
  float* m2        = (float*)alloc((size_t)BG * NHID * 4);
  unsigned short* Wp1 = (unsigned short*)alloc(2048 * 8 * 2);
  unsigned short* Wp2 = (unsigned short*)alloc(2048 * 8 * 2);
  unsigned short* Wp3 = (unsigned short*)alloc(2048 * 8 * 2);
  unsigned short* Wp4 = (unsigned short*)alloc(2048 * 8 * 2);

  hipMemsetAsync(indeg, 0, (size_t)2 * N_NODES * 4, stream);
  hipMemsetAsync(stats, 0, 4 * 256 * 4, stream);

  // CSR build
  hist_kernel<<<(N_EDGES + 255) / 256, 256, 0, stream>>>(dst, indeg);
  scan_chunks<<<98, 256, 0, stream>>>(indeg, rowstart, chunksum);
  scan_sums<<<1, 128, 0, stream>>>(chunksum, 98);
  scan_add<<<(N_NODES + 256) / 256, 256, 0, stream>>>(rowstart, chunksum);
  compute_dinv<<<(N_NODES + 255) / 256, 256, 0, stream>>>(indeg, dinv);
  scatter_edges<<<(N_EDGES + 255) / 256, 256, 0, stream>>>(src, dst, rowstart, cursor, dinv, csr_sw);

  // bf16 prep
  const int el2_blocks = (N_NODES * 64 + 255) / 256;   // float2 granularity (cast)
  const int el4_blocks = (N_NODES * 32 + 255) / 256;   // float4 granularity (bn)
  cast_bf16_kernel<<<el2_blocks, 256, 0, stream>>>((const float2*)x_in, xb);
  pack_w_kernel<<<8, 256, 0, stream>>>(W1, Wp1);
  pack_w_kernel<<<8, 256, 0, stream>>>(W2, Wp2);
  pack_w_kernel<<<8, 256, 0, stream>>>(W3, Wp3);
  pack_w_kernel<<<8, 256, 0, stream>>>(Wa, Wp4);

  const int gemm_blocks_m = (N_NODES + 127) / 128;  // 782
  const int AGG_BLOCKS = 2048;

  const unsigned short* Wps[3] = {Wp1, Wp2, Wp3};
  const float* gs[3] = {g1, g2, g3};
  const float* bes[3] = {be1, be2, be3};
  for (int l = 0; l < 3; ++l) {
    gemm_mfma<<<gemm_blocks_m, 256, 0, stream>>>(xb, Wps[l], Hb, N_NODES);
    agg_kernel<0><<<AGG_BLOCKS, 256, 0, stream>>>((const uint2*)Hb, rowstart, csr_sw, dinv,
                                                  nullptr, nullptr, (float4*)agg, stats + l * 256);
    bn_relu_res<<<el4_blocks, 256, 0, stream>>>((const float4*)agg, stats + l * 256,
                                                gs[l], bes[l], (uint2*)xb);
  }

  // GAT layer
  gemm_mfma<<<gemm_blocks_m, 256, 0, stream>>>(xb, Wp4, Hb, N_NODES);
  compute_esed<<<(N_NODES + 3) / 4, 256, 0, stream>>>(Hb, asrc, adst, es, ed);
  gat_prep_node<<<(N_NODES + 255) / 256, 256, 0, stream>>>(csr_sw, rowstart, es, ed, wselfa, winv);
  agg_kernel<1><<<AGG_BLOCKS, 256, 0, stream>>>((const uint2*)Hb, rowstart, csr_sw, nullptr,
                                                wselfa, winv, (float4*)agg, stats + 3 * 256);
  bn_relu_res<<<el4_blocks, 256, 0, stream>>>((const float4*)agg, stats + 3 * 256,
                                              ga, bea, (uint2*)xb);

  // pooling
  graph_starts<<<(N_NODES + 255) / 256, 256, 0, stream>>>(batch, gstart);
  pool_kernel<<<BG, 256, 0, stream>>>(xb, gstart, pooled);

  // MLP head (f32)
  gemm_f32<1, 1><<<dim3(4, 4), 256, 0, stream>>>(pooled, Wh1, bh1, m1, BG, CCH, NHID);
  gemm_f32<1, 1><<<dim3(4, 4), 256, 0, stream>>>(m1, Wm0, bm0, m2, BG, NHID, NHID);
  gemm_f32<1, 1><<<dim3(4, 4), 256, 0, stream>>>(m2, Wm1, bm1, m1, BG, NHID, NHID);
  gemm_f32<0, 1><<<dim3(4, 2), 256, 0, stream>>>(m1, Wo, bo, (float*)d_out, BG, NHID, NOUT);
}

// Round 6
// 1157.914 us; speedup vs baseline: 1.0374x; 1.0374x over previous
//
#include <hip/hip_runtime.h>

// Problem constants (match reference)
#define N_NODES 100000
#define N_EDGES 1600000
#define CCH     128
#define BG      512
#define NHID    512
#define NOUT    256
#define BN_EPS  1e-5f

typedef __attribute__((ext_vector_type(8))) short s16x8;
typedef __attribute__((ext_vector_type(4))) float f32x4;

static __device__ __forceinline__ float leaky(float x) { return x > 0.f ? x : 0.2f * x; }
static __device__ __forceinline__ uint32_t bfr16(float x) {
  uint32_t u = __float_as_uint(x);
  u += 0x7fffu + ((u >> 16) & 1u);
  return u >> 16;
}
static __device__ __forceinline__ uint32_t pack2(float a, float b) {
  return bfr16(a) | (bfr16(b) << 16);
}
static __device__ __forceinline__ float blo(uint32_t u) { return __uint_as_float(u << 16); }
static __device__ __forceinline__ float bhi(uint32_t u) { return __uint_as_float(u & 0xffff0000u); }

// ---------------- graph prep ----------------
__global__ void hist_kernel(const int* __restrict__ dst, int* __restrict__ indeg) {
  int e = blockIdx.x * 256 + threadIdx.x;
  if (e < N_EDGES) atomicAdd(&indeg[dst[e]], 1);
}

__global__ __launch_bounds__(256) void scan_chunks(const int* __restrict__ indeg,
                                                   int* __restrict__ rowstart,
                                                   int* __restrict__ chunksum) {
  int tid = threadIdx.x;
  int base = blockIdx.x * 1024 + tid * 4;
  int4 v;
  if (base + 3 < N_NODES) {
    v = *(const int4*)(indeg + base);
  } else {
    v.x = (base + 0 < N_NODES) ? indeg[base + 0] : 0;
    v.y = (base + 1 < N_NODES) ? indeg[base + 1] : 0;
    v.z = (base + 2 < N_NODES) ? indeg[base + 2] : 0;
    v.w = (base + 3 < N_NODES) ? indeg[base + 3] : 0;
  }
  int s = v.x + v.y + v.z + v.w;
  __shared__ int ss[256];
  ss[tid] = s;
  __syncthreads();
  for (int off = 1; off < 256; off <<= 1) {
    int t = (tid >= off) ? ss[tid - off] : 0;
    __syncthreads();
    ss[tid] += t;
    __syncthreads();
  }
  int excl = ss[tid] - s;
  if (base + 0 < N_NODES) rowstart[base + 0] = excl;
  if (base + 1 < N_NODES) rowstart[base + 1] = excl + v.x;
  if (base + 2 < N_NODES) rowstart[base + 2] = excl + v.x + v.y;
  if (base + 3 < N_NODES) rowstart[base + 3] = excl + v.x + v.y + v.z;
  if (tid == 255) chunksum[blockIdx.x] = ss[255];
}

__global__ void scan_sums(int* __restrict__ chunksum, int nch) {
  __shared__ int ss[128];
  int tid = threadIdx.x;
  int v = (tid < nch) ? chunksum[tid] : 0;
  ss[tid] = v;
  __syncthreads();
  for (int off = 1; off < 128; off <<= 1) {
    int t = (tid >= off) ? ss[tid - off] : 0;
    __syncthreads();
    ss[tid] += t;
    __syncthreads();
  }
  if (tid < nch) chunksum[tid] = ss[tid] - v;  // exclusive
}

// merged: scan finalize + dinv
__global__ void scan_add_dinv(int* __restrict__ rowstart, const int* __restrict__ chunksum,
                              const int* __restrict__ indeg, float* __restrict__ dinv) {
  int i = blockIdx.x * 256 + threadIdx.x;
  if (i < N_NODES) {
    rowstart[i] += chunksum[i >> 10];
    dinv[i] = rsqrtf((float)(indeg[i] + 1));
  } else if (i == N_NODES) {
    rowstart[N_NODES] = N_EDGES;
  }
}

__global__ void scatter_edges(const int* __restrict__ src, const int* __restrict__ dst,
                              const int* __restrict__ rowstart, int* __restrict__ cursor,
                              const float* __restrict__ dinv, int2* __restrict__ csr_sw) {
  int e = blockIdx.x * 256 + threadIdx.x;
  if (e < N_EDGES) {
    int d = dst[e];
    int s = src[e];
    int p = rowstart[d] + atomicAdd(&cursor[d], 1);
    float w = dinv[s] * dinv[d];
    csr_sw[p] = make_int2(s, __float_as_int(w));
  }
}

// ---------------- prep: cast x to bf16 + pack 4 weight matrices ----------------
// grid = 25000 (cast) + 32 (4 W x 8 blocks)
__global__ void prep_kernel(const float2* __restrict__ x2, uint32_t* __restrict__ xb,
                            const float* __restrict__ W1, const float* __restrict__ W2,
                            const float* __restrict__ W3, const float* __restrict__ W4,
                            unsigned short* __restrict__ Wp1, unsigned short* __restrict__ Wp2,
                            unsigned short* __restrict__ Wp3, unsigned short* __restrict__ Wp4) {
  int b = blockIdx.x;
  if (b < 25000) {
    size_t idx = (size_t)b * 256 + threadIdx.x;
    float2 v = x2[idx];
    xb[idx] = pack2(v.x, v.y);
    return;
  }
  int pb = b - 25000;            // 0..31
  int wsel = pb >> 3;            // 0..3
  int t = (pb & 7) * 256 + threadIdx.x;  // 0..2047
  const float* W = (wsel == 0) ? W1 : (wsel == 1) ? W2 : (wsel == 2) ? W3 : W4;
  unsigned short* Wp = (wsel == 0) ? Wp1 : (wsel == 1) ? Wp2 : (wsel == 2) ? Wp3 : Wp4;
  int lane = t & 63;
  int ks = (t >> 6) & 3;
  int nt = t >> 8;
  int c = nt * 16 + (lane & 15);
  int kb = ks * 32 + (lane >> 4) * 8;
#pragma unroll
  for (int i = 0; i < 8; ++i)
    Wp[(size_t)t * 8 + i] = (unsigned short)bfr16(W[(size_t)(kb + i) * 128 + c]);
}

// ---------------- MFMA conv GEMM, optionally fusing BN+ReLU+residual on the A side ------
// FUSE=1: xnew = relu(bn(agg)) + xold; writes xnew back to xbm AND uses it as A.
template <int FUSE>
__global__ __launch_bounds__(256) void gemm_mfma(uint32_t* __restrict__ xbm,          // [M][64] bf16 pairs (rw if FUSE)
                                                 const float* __restrict__ aggf,       // [M][128] f32
                                                 const float* __restrict__ stats,
                                                 const float* __restrict__ gamma,
                                                 const float* __restrict__ beta,
                                                 const unsigned short* __restrict__ Wp,
                                                 uint32_t* __restrict__ Hb,            // [M][64] bf16 pairs
                                                 int M) {
  __shared__ float scs[128], bcs[128];
  if (FUSE) {
    int t = threadIdx.x;
    if (t < 128) {
      const float n_inv = 1.f / (float)N_NODES;
      float m = stats[t] * n_inv;
      float v = stats[128 + t] * n_inv - m * m;
      float s = gamma[t] * rsqrtf(v + BN_EPS);
      scs[t] = s;
      bcs[t] = beta[t] - m * s;
    }
    __syncthreads();
  }
  int wave = threadIdx.x >> 6, lane = threadIdx.x & 63;
  int row0 = blockIdx.x * 128 + wave * 32;
  int r = lane & 15, g = lane >> 4;

  f32x4 acc[2][8];
#pragma unroll
  for (int mt = 0; mt < 2; ++mt)
#pragma unroll
    for (int nt = 0; nt < 8; ++nt) acc[mt][nt] = (f32x4){0.f, 0.f, 0.f, 0.f};

  s16x8 a[2][4];
#pragma unroll
  for (int mt = 0; mt < 2; ++mt) {
    int row = row0 + mt * 16 + r;
    bool v = row < M;
    if (FUSE) {
#pragma unroll
      for (int ks = 0; ks < 4; ++ks) {
        int ch = ks * 32 + g * 8;
        s16x8 af = {0, 0, 0, 0, 0, 0, 0, 0};
        if (v) {
          const float4* ap = (const float4*)(aggf + (size_t)row * 128 + ch);
          float4 a0 = ap[0], a1 = ap[1];
          uint4 xo = *(const uint4*)(xbm + (size_t)row * 64 + (ch >> 1));
          float aa[8] = {a0.x, a0.y, a0.z, a0.w, a1.x, a1.y, a1.z, a1.w};
          float xold[8] = {blo(xo.x), bhi(xo.x), blo(xo.y), bhi(xo.y),
                           blo(xo.z), bhi(xo.z), blo(xo.w), bhi(xo.w)};
          uint32_t pk[4];
#pragma unroll
          for (int jj = 0; jj < 4; ++jj) {
            float r0v = fmaxf(fmaf(aa[2 * jj],     scs[ch + 2 * jj],     bcs[ch + 2 * jj]),     0.f) + xold[2 * jj];
            float r1v = fmaxf(fmaf(aa[2 * jj + 1], scs[ch + 2 * jj + 1], bcs[ch + 2 * jj + 1]), 0.f) + xold[2 * jj + 1];
            pk[jj] = pack2(r0v, r1v);
          }
          uint4 st = make_uint4(pk[0], pk[1], pk[2], pk[3]);
          *(uint4*)(xbm + (size_t)row * 64 + (ch >> 1)) = st;
          af = *(s16x8*)&st;
        }
        a[mt][ks] = af;
      }
    } else {
      const unsigned short* ap = (const unsigned short*)xbm + (size_t)row * 128 + g * 8;
#pragma unroll
      for (int ks = 0; ks < 4; ++ks) {
        s16x8 af = {0, 0, 0, 0, 0, 0, 0, 0};
        if (v) af = *(const s16x8*)(ap + ks * 32);
        a[mt][ks] = af;
      }
    }
  }
#pragma unroll
  for (int ks = 0; ks < 4; ++ks) {
#pragma unroll
    for (int nt = 0; nt < 8; ++nt) {
      s16x8 bfr = *(const s16x8*)(Wp + ((size_t)(nt * 4 + ks) * 64 + lane) * 8);
      acc[0][nt] = __builtin_amdgcn_mfma_f32_16x16x32_bf16(a[0][ks], bfr, acc[0][nt], 0, 0, 0);
      acc[1][nt] = __builtin_amdgcn_mfma_f32_16x16x32_bf16(a[1][ks], bfr, acc[1][nt], 0, 0, 0);
    }
  }
#pragma unroll
  for (int mt = 0; mt < 2; ++mt) {
#pragma unroll
    for (int nt = 0; nt < 8; ++nt) {
#pragma unroll
      for (int reg = 0; reg < 4; ++reg) {
        float v0 = acc[mt][nt][reg];
        float v1 = __shfl_xor(v0, 1);
        int row = row0 + mt * 16 + (lane >> 4) * 4 + reg;
        int col = nt * 16 + (lane & 15);
        if (!(lane & 1) && row < M)
          Hb[(size_t)row * 64 + (col >> 1)] = pack2(v0, v1);
      }
    }
  }
}

// ---------------- unified aggregation: 2 nodes/wave, depth-2 pipelined gathers + BN stats ----
// GCN: pack.y = dinv[s]*dinv[d].  GAT: pack.y = es[src]; weight = exp(leaky(es+ed)) inline,
// denominator via lane-strided pass, final scale by 1/sum.
template <int GAT>
__global__ __launch_bounds__(256) void agg_kernel(const uint2* __restrict__ Hb2,
                                                  const int* __restrict__ rowstart,
                                                  const int2* __restrict__ pack,
                                                  const float* __restrict__ dinv,
                                                  const float* __restrict__ es,
                                                  const float* __restrict__ ed,
                                                  float4* __restrict__ agg4,
                                                  float* __restrict__ stats) {
  int tid = threadIdx.x;
  int lane = tid & 63;
  int hl = lane & 31;
  int half = lane >> 5;
  int gw = (blockIdx.x * 256 + tid) >> 6;
  int nw = (gridDim.x * 256) >> 6;
  float s0 = 0, s1 = 0, s2 = 0, s3 = 0, q0 = 0, q1 = 0, q2 = 0, q3 = 0;
  for (int pi = gw; pi < N_NODES / 2; pi += nw) {
    int n = 2 * pi + half;
    int e0 = rowstart[n], e1 = rowstart[n + 1];
    int len = e1 - e0;
    int G = (len + 3) >> 2;
    int Gmax = max(G, __shfl_xor(G, 32));
    int ecl = (len > 0) ? (e1 - 1) : 0;
    float edi = 0.f, selfw, fscale = 1.f;
    if (GAT) {
      edi = ed[n];
      float wself = __expf(leaky(es[n] + edi));
      float wsum = (hl == 0) ? wself : 0.f;
      for (int e = e0 + hl; e < e1; e += 32)
        wsum += __expf(leaky(__int_as_float(pack[e].y) + edi));
#pragma unroll
      for (int off = 16; off; off >>= 1) wsum += __shfl_xor(wsum, off);
      fscale = 1.f / (wsum + 1e-16f);
      selfw = wself;
    } else {
      float di = dinv[n];
      selfw = di * di;
    }
#define EDGEW(py, ok) (GAT ? ((ok) ? __expf(leaky(__int_as_float(py) + edi)) : 0.f) \
                           : ((ok) ? __int_as_float(py) : 0.f))
    uint2 hs = Hb2[(size_t)n * 32 + hl];
    float c0 = blo(hs.x) * selfw, c1 = bhi(hs.x) * selfw;
    float c2 = blo(hs.y) * selfw, c3 = bhi(hs.y) * selfw;

    if (Gmax > 0) {
      uint2 rA0, rA1, rA2, rA3;
      float wA0, wA1, wA2, wA3;
      int iB0 = 0, iB1 = 0, iB2 = 0, iB3 = 0;
      float wB0 = 0, wB1 = 0, wB2 = 0, wB3 = 0;
      {
        int e = e0;
        int2 pa = pack[e < e1 ? e : ecl];
        int2 pb = pack[e + 1 < e1 ? e + 1 : ecl];
        int2 pc = pack[e + 2 < e1 ? e + 2 : ecl];
        int2 pd = pack[e + 3 < e1 ? e + 3 : ecl];
        wA0 = EDGEW(pa.y, e < e1);
        wA1 = EDGEW(pb.y, e + 1 < e1);
        wA2 = EDGEW(pc.y, e + 2 < e1);
        wA3 = EDGEW(pd.y, e + 3 < e1);
        rA0 = Hb2[(size_t)pa.x * 32 + hl];
        rA1 = Hb2[(size_t)pb.x * 32 + hl];
        rA2 = Hb2[(size_t)pc.x * 32 + hl];
        rA3 = Hb2[(size_t)pd.x * 32 + hl];
      }
      if (Gmax > 1) {
        int e = e0 + 4;
        int2 pa = pack[e < e1 ? e : ecl];
        int2 pb = pack[e + 1 < e1 ? e + 1 : ecl];
        int2 pc = pack[e + 2 < e1 ? e + 2 : ecl];
        int2 pd = pack[e + 3 < e1 ? e + 3 : ecl];
        iB0 = pa.x; wB0 = EDGEW(pa.y, e < e1);
        iB1 = pb.x; wB1 = EDGEW(pb.y, e + 1 < e1);
        iB2 = pc.x; wB2 = EDGEW(pc.y, e + 2 < e1);
        iB3 = pd.x; wB3 = EDGEW(pd.y, e + 3 < e1);
      }
      for (int g = 0; g < Gmax; ++g) {
        uint2 rB0, rB1, rB2, rB3;
        int nI0, nI1, nI2, nI3;
        float nw0, nw1, nw2, nw3;
        if (g + 1 < Gmax) {
          rB0 = Hb2[(size_t)iB0 * 32 + hl];
          rB1 = Hb2[(size_t)iB1 * 32 + hl];
          rB2 = Hb2[(size_t)iB2 * 32 + hl];
          rB3 = Hb2[(size_t)iB3 * 32 + hl];
        }
        if (g + 2 < Gmax) {
          int e = e0 + (g + 2) * 4;
          int2 pa = pack[e < e1 ? e : ecl];
          int2 pb = pack[e + 1 < e1 ? e + 1 : ecl];
          int2 pc = pack[e + 2 < e1 ? e + 2 : ecl];
          int2 pd = pack[e + 3 < e1 ? e + 3 : ecl];
          nI0 = pa.x; nw0 = EDGEW(pa.y, e < e1);
          nI1 = pb.x; nw1 = EDGEW(pb.y, e + 1 < e1);
          nI2 = pc.x; nw2 = EDGEW(pc.y, e + 2 < e1);
          nI3 = pd.x; nw3 = EDGEW(pd.y, e + 3 < e1);
        }
        c0 = fmaf(blo(rA0.x), wA0, c0); c1 = fmaf(bhi(rA0.x), wA0, c1);
        c2 = fmaf(blo(rA0.y), wA0, c2); c3 = fmaf(bhi(rA0.y), wA0, c3);
        c0 = fmaf(blo(rA1.x), wA1, c0); c1 = fmaf(bhi(rA1.x), wA1, c1);
        c2 = fmaf(blo(rA1.y), wA1, c2); c3 = fmaf(bhi(rA1.y), wA1, c3);
        c0 = fmaf(blo(rA2.x), wA2, c0); c1 = fmaf(bhi(rA2.x), wA2, c1);
        c2 = fmaf(blo(rA2.y), wA2, c2); c3 = fmaf(bhi(rA2.y), wA2, c3);
        c0 = fmaf(blo(rA3.x), wA3, c0); c1 = fmaf(bhi(rA3.x), wA3, c1);
        c2 = fmaf(blo(rA3.y), wA3, c2); c3 = fmaf(bhi(rA3.y), wA3, c3);
        rA0 = rB0; rA1 = rB1; rA2 = rB2; rA3 = rB3;
        wA0 = wB0; wA1 = wB1; wA2 = wB2; wA3 = wB3;
        iB0 = nI0; iB1 = nI1; iB2 = nI2; iB3 = nI3;
        wB0 = nw0; wB1 = nw1; wB2 = nw2; wB3 = nw3;
      }
    }
#undef EDGEW
    if (GAT) { c0 *= fscale; c1 *= fscale; c2 *= fscale; c3 *= fscale; }
    agg4[(size_t)n * 32 + hl] = make_float4(c0, c1, c2, c3);
    s0 += c0; s1 += c1; s2 += c2; s3 += c3;
    q0 += c0 * c0; q1 += c1 * c1; q2 += c2 * c2; q3 += c3 * c3;
  }
  s0 += __shfl_xor(s0, 32); s1 += __shfl_xor(s1, 32);
  s2 += __shfl_xor(s2, 32); s3 += __shfl_xor(s3, 32);
  q0 += __shfl_xor(q0, 32); q1 += __shfl_xor(q1, 32);
  q2 += __shfl_xor(q2, 32); q3 += __shfl_xor(q3, 32);
  __shared__ float red[4][128];
  int w = tid >> 6;
  if (half == 0) {
    red[w][4 * hl + 0] = s0; red[w][4 * hl + 1] = s1;
    red[w][4 * hl + 2] = s2; red[w][4 * hl + 3] = s3;
  }
  __syncthreads();
  if (w == 0) {
    float a = red[0][2 * lane] + red[1][2 * lane] + red[2][2 * lane] + red[3][2 * lane];
    float b = red[0][2 * lane + 1] + red[1][2 * lane + 1] + red[2][2 * lane + 1] + red[3][2 * lane + 1];
    atomicAdd(&stats[2 * lane], a);
    atomicAdd(&stats[2 * lane + 1], b);
  }
  __syncthreads();
  if (half == 0) {
    red[w][4 * hl + 0] = q0; red[w][4 * hl + 1] = q1;
    red[w][4 * hl + 2] = q2; red[w][4 * hl + 3] = q3;
  }
  __syncthreads();
  if (w == 0) {
    float a = red[0][2 * lane] + red[1][2 * lane] + red[2][2 * lane] + red[3][2 * lane];
    float b = red[0][2 * lane + 1] + red[1][2 * lane + 1] + red[2][2 * lane + 1] + red[3][2 * lane + 1];
    atomicAdd(&stats[128 + 2 * lane], a);
    atomicAdd(&stats[128 + 2 * lane + 1], b);
  }
}

// ---------------- es/ed for GAT ----------------
__global__ __launch_bounds__(256) void compute_esed(const uint32_t* __restrict__ Hb,
                                                    const float* __restrict__ asrc,
                                                    const float* __restrict__ adst,
                                                    float* __restrict__ es, float* __restrict__ ed) {
  int lane = threadIdx.x & 63;
  int gwave = (blockIdx.x * 256 + threadIdx.x) >> 6;
  if (gwave >= N_NODES) return;
  float2 av = ((const float2*)asrc)[lane];
  float2 dv = ((const float2*)adst)[lane];
  uint32_t hv = Hb[(size_t)gwave * 64 + lane];
  float hx = blo(hv), hy = bhi(hv);
  float e_s = hx * av.x + hy * av.y;
  float e_d = hx * dv.x + hy * dv.y;
  for (int off = 32; off; off >>= 1) {
    e_s += __shfl_down(e_s, off);
    e_d += __shfl_down(e_d, off);
  }
  if (lane == 0) { es[gwave] = e_s; ed[gwave] = e_d; }
}

// overwrite pack.y with es[src]
__global__ void gat_pack_kernel(int2* __restrict__ sw, const float* __restrict__ es) {
  int e = blockIdx.x * 256 + threadIdx.x;
  if (e < N_EDGES) {
    int2 v = sw[e];
    v.y = __float_as_int(es[v.x]);
    sw[e] = v;
  }
}

// ---------------- pooling with fused BN+ReLU+residual of the last layer ----------------
__global__ void graph_starts(const int* __restrict__ batch, int* __restrict__ gstart) {
  int n = blockIdx.x * 256 + threadIdx.x;
  if (n >= N_NODES) return;
  int b = batch[n];
  int bp = (n == 0) ? -1 : batch[n - 1];
  for (int g = bp + 1; g <= b; ++g) gstart[g] = n;
  if (n == N_NODES - 1) {
    for (int g = b + 1; g <= BG; ++g) gstart[g] = N_NODES;
  }
}

__global__ __launch_bounds__(256) void pool_bn(const float* __restrict__ aggf,   // [N][128]
                                               const uint32_t* __restrict__ xb,  // [N][64]
                                               const float* __restrict__ stats,
                                               const float* __restrict__ gamma,
                                               const float* __restrict__ beta,
                                               const int* __restrict__ gstart,
                                               float* __restrict__ pooled) {
  int g = blockIdx.x;
  int c = threadIdx.x & 127;
  int half = threadIdx.x >> 7;
  const float n_inv = 1.f / (float)N_NODES;
  float m = stats[c] * n_inv;
  float v = stats[128 + c] * n_inv - m * m;
  float sc = gamma[c] * rsqrtf(v + BN_EPS);
  float bc = beta[c] - m * sc;
  int s = gstart[g], e = gstart[g + 1];
  float acc = 0.f;
  for (int n = s + half; n < e; n += 2) {
    float a = aggf[(size_t)n * 128 + c];
    uint32_t u = xb[(size_t)n * 64 + (c >> 1)];
    float xo = (c & 1) ? bhi(u) : blo(u);
    acc += fmaxf(fmaf(a, sc, bc), 0.f) + xo;
  }
  __shared__ float red[256];
  red[threadIdx.x] = acc;
  __syncthreads();
  if (half == 0) {
    float vsum = red[c] + red[128 + c];
    int cnt = e - s;
    pooled[(size_t)g * 128 + c] = vsum / fmaxf((float)cnt, 1.f);
  }
}

// ---------------- f32 GEMM (MLP head only) ----------------
template <int RELU, int BIAS>
__global__ __launch_bounds__(256) void gemm_f32(const float* __restrict__ A,
                                                const float* __restrict__ W,
                                                const float* __restrict__ bias,
                                                float* __restrict__ Cmat,
                                                int M, int K, int N) {
  __shared__ float As[32][128];
  __shared__ float Bs[32][128];
  int tid = threadIdx.x;
  int row0 = blockIdx.x * 128, col0 = blockIdx.y * 128;
  int tx = tid & 15, ty = tid >> 4;
  float acc[8][8];
#pragma unroll
  for (int i = 0; i < 8; ++i)
#pragma unroll
    for (int j = 0; j < 8; ++j) acc[i][j] = 0.f;

  for (int k0 = 0; k0 < K; k0 += 32) {
    {
      int r = tid >> 1;
      int kseg = (tid & 1) * 16;
      bool valid = (row0 + r) < M;
      const float* ap = A + (size_t)(row0 + r) * K + k0 + kseg;
#pragma unroll
      for (int q = 0; q < 4; ++q) {
        float4 v;
        if (valid) v = *(const float4*)(ap + q * 4);
        else { v.x = v.y = v.z = v.w = 0.f; }
        As[kseg + q * 4 + 0][r] = v.x;
        As[kseg + q * 4 + 1][r] = v.y;
        As[kseg + q * 4 + 2][r] = v.z;
        As[kseg + q * 4 + 3][r] = v.w;
      }
    }
    {
      int kk = tid >> 3;
      int seg = (tid & 7) * 16;
      const float* wp = W + (size_t)(k0 + kk) * N + col0 + seg;
#pragma unroll
      for (int q = 0; q < 4; ++q)
        *(float4*)&Bs[kk][seg + q * 4] = *(const float4*)(wp + q * 4);
    }
    __syncthreads();
#pragma unroll
    for (int kk = 0; kk < 32; ++kk) {
      float4 a0 = *(const float4*)&As[kk][ty * 4];
      float4 a1 = *(const float4*)&As[kk][64 + ty * 4];
      float4 b0 = *(const float4*)&Bs[kk][tx * 4];
      float4 b1 = *(const float4*)&Bs[kk][64 + tx * 4];
      float av[8] = {a0.x, a0.y, a0.z, a0.w, a1.x, a1.y, a1.z, a1.w};
      float bv[8] = {b0.x, b0.y, b0.z, b0.w, b1.x, b1.y, b1.z, b1.w};
#pragma unroll
      for (int i = 0; i < 8; ++i)
#pragma unroll
        for (int j = 0; j < 8; ++j) acc[i][j] = fmaf(av[i], bv[j], acc[i][j]);
    }
    __syncthreads();
  }
#pragma unroll
  for (int i = 0; i < 8; ++i) {
    int r = row0 + ((i < 4) ? (ty * 4 + i) : (64 + ty * 4 + i - 4));
    if (r >= M) continue;
#pragma unroll
    for (int j = 0; j < 8; ++j) {
      int c = col0 + ((j < 4) ? (tx * 4 + j) : (64 + tx * 4 + j - 4));
      float v = acc[i][j];
      if (BIAS) v += bias[c];
      if (RELU) v = fmaxf(v, 0.f);
      Cmat[(size_t)r * N + c] = v;
    }
  }
}

// ---------------- host launch ----------------
extern "C" void kernel_launch(void* const* d_in, const int* in_sizes, int n_in,
                              void* d_out, int out_size, void* d_ws, size_t ws_size,
                              hipStream_t stream) {
  const float* x_in  = (const float*)d_in[0];
  const int*   eidx  = (const int*)d_in[1];
  const int*   batch = (const int*)d_in[2];
  const float* W1 = (const float*)d_in[3];
  const float* g1 = (const float*)d_in[5];
  const float* be1 = (const float*)d_in[6];
  const float* W2 = (const float*)d_in[7];
  const float* g2 = (const float*)d_in[9];
  const float* be2 = (const float*)d_in[10];
  const float* W3 = (const float*)d_in[11];
  const float* g3 = (const float*)d_in[13];
  const float* be3 = (const float*)d_in[14];
  const float* Wa = (const float*)d_in[15];
  const float* asrc = (const float*)d_in[16];
  const float* adst = (const float*)d_in[17];
  const float* ga = (const float*)d_in[19];
  const float* bea = (const float*)d_in[20];
  const float* Wh1 = (const float*)d_in[21];
  const float* bh1 = (const float*)d_in[22];
  const float* Wm0 = (const float*)d_in[23];
  const float* bm0 = (const float*)d_in[24];
  const float* Wm1 = (const float*)d_in[25];
  const float* bm1 = (const float*)d_in[26];
  const float* Wo = (const float*)d_in[27];
  const float* bo = (const float*)d_in[28];

  const int* src = eidx;
  const int* dst = eidx + N_EDGES;

  char* p = (char*)d_ws;
  auto alloc = [&](size_t bytes) {
    char* r = p;
    p += (bytes + 255) & ~(size_t)255;
    return r;
  };
  uint32_t* Hb     = (uint32_t*)alloc((size_t)N_NODES * 64 * 4);   // bf16-pair h
  uint32_t* xb     = (uint32_t*)alloc((size_t)N_NODES * 64 * 4);   // bf16-pair x
  float* agg       = (float*)alloc((size_t)N_NODES * CCH * 4);
  int2*  csr_sw    = (int2*)alloc((size_t)N_EDGES * 8);
  int*   rowstart  = (int*)alloc((size_t)(N_NODES + 1) * 4);
  int*   indeg     = (int*)alloc((size_t)2 * N_NODES * 4);
  int*   cursor    = indeg + N_NODES;
  float* dinv      = (float*)alloc((size_t)N_NODES * 4);
  float* es        = (float*)alloc((size_t)N_NODES * 4);
  float* ed        = (float*)alloc((size_t)N_NODES * 4);
  int*   chunksum  = (int*)alloc(128 * 4);
  float* stats     = (float*)alloc(4 * 256 * 4);
  int*   gstart    = (int*)alloc((BG + 1) * 4);
  float* pooled    = (float*)alloc((size_t)BG * CCH * 4);
  float* m1        = (float*)alloc((size_t)BG * NHID * 4);
  float* m2        = (float*)alloc((size_t)BG * NHID * 4);
  unsigned short* Wp1 = (unsigned short*)alloc(2048 * 8 * 2);
  unsigned short* Wp2 = (unsigned short*)alloc(2048 * 8 * 2);
  unsigned short* Wp3 = (unsigned short*)alloc(2048 * 8 * 2);
  unsigned short* Wp4 = (unsigned short*)alloc(2048 * 8 * 2);

  hipMemsetAsync(indeg, 0, (size_t)2 * N_NODES * 4, stream);
  hipMemsetAsync(stats, 0, 4 * 256 * 4, stream);

  // CSR build
  hist_kernel<<<(N_EDGES + 255) / 256, 256, 0, stream>>>(dst, indeg);
  scan_chunks<<<98, 256, 0, stream>>>(indeg, rowstart, chunksum);
  scan_sums<<<1, 128, 0, stream>>>(chunksum, 98);
  scan_add_dinv<<<(N_NODES + 256) / 256, 256, 0, stream>>>(rowstart, chunksum, indeg, dinv);
  scatter_edges<<<(N_EDGES + 255) / 256, 256, 0, stream>>>(src, dst, rowstart, cursor, dinv, csr_sw);

  // prep: cast x + pack 4 weights
  prep_kernel<<<25000 + 32, 256, 0, stream>>>((const float2*)x_in, xb, W1, W2, W3, Wa,
                                              Wp1, Wp2, Wp3, Wp4);

  const int gemm_blocks_m = (N_NODES + 127) / 128;  // 782
  const int AGG_BLOCKS = 2048;

  // layer 1 (no BN fusion; xb fresh from cast)
  gemm_mfma<0><<<gemm_blocks_m, 256, 0, stream>>>(xb, nullptr, nullptr, nullptr, nullptr,
                                                  Wp1, Hb, N_NODES);
  agg_kernel<0><<<AGG_BLOCKS, 256, 0, stream>>>((const uint2*)Hb, rowstart, csr_sw, dinv,
                                                nullptr, nullptr, (float4*)agg, stats + 0 * 256);
  // layer 2 (fuse BN of layer 1)
  gemm_mfma<1><<<gemm_blocks_m, 256, 0, stream>>>(xb, agg, stats + 0 * 256, g1, be1,
                                                  Wp2, Hb, N_NODES);
  agg_kernel<0><<<AGG_BLOCKS, 256, 0, stream>>>((const uint2*)Hb, rowstart, csr_sw, dinv,
                                                nullptr, nullptr, (float4*)agg, stats + 1 * 256);
  // layer 3 (fuse BN of layer 2)
  gemm_mfma<1><<<gemm_blocks_m, 256, 0, stream>>>(xb, agg, stats + 1 * 256, g2, be2,
                                                  Wp3, Hb, N_NODES);
  agg_kernel<0><<<AGG_BLOCKS, 256, 0, stream>>>((const uint2*)Hb, rowstart, csr_sw, dinv,
                                                nullptr, nullptr, (float4*)agg, stats + 2 * 256);
  // layer 4 = GAT (fuse BN of layer 3)
  gemm_mfma<1><<<gemm_blocks_m, 256, 0, stream>>>(xb, agg, stats + 2 * 256, g3, be3,
                                                  Wp4, Hb, N_NODES);
  compute_esed<<<(N_NODES + 3) / 4, 256, 0, stream>>>(Hb, asrc, adst, es, ed);
  gat_pack_kernel<<<(N_EDGES + 255) / 256, 256, 0, stream>>>(csr_sw, es);
  agg_kernel<1><<<AGG_BLOCKS, 256, 0, stream>>>((const uint2*)Hb, rowstart, csr_sw, nullptr,
                                                es, ed, (float4*)agg, stats + 3 * 256);

  // pooling (fuses BN of GAT layer)
  graph_starts<<<(N_NODES + 255) / 256, 256, 0, stream>>>(batch, gstart);
  pool_bn<<<BG, 256, 0, stream>>>(agg, xb, stats + 3 * 256, ga, bea, gstart, pooled);

  // MLP head (f32)
  gemm_f32<1, 1><<<dim3(4, 4), 256, 0, stream>>>(pooled, Wh1, bh1, m1, BG, CCH, NHID);
  gemm_f32<1, 1><<<dim3(4, 4), 256, 0, stream>>>(m1, Wm0, bm0, m2, BG, NHID, NHID);
  gemm_f32<1, 1><<<dim3(4, 4), 256, 0, stream>>>(m2, Wm1, bm1, m1, BG, NHID, NHID);
  gemm_f32<0, 1><<<dim3(4, 2), 256, 0, stream>>>(m1, Wo, bo, (float*)d_out, BG, NHID, NOUT);
}

// Round 7
// 1040.573 us; speedup vs baseline: 1.1544x; 1.1128x over previous
//
#include <hip/hip_runtime.h>

// Problem constants (match reference)
#define N_NODES 100000
#define N_EDGES 1600000
#define CCH     128
#define BG      512
#define NHID    512
#define NOUT    256
#define BN_EPS  1e-5f
// padded CSR capacity: sum ceil(d/4)*4 <= E + 3N, +128 tail pad
#define CSR_CAP (N_EDGES + 4 * N_NODES + 128)

typedef __attribute__((ext_vector_type(8))) short s16x8;
typedef __attribute__((ext_vector_type(4))) float f32x4;

static __device__ __forceinline__ float leaky(float x) { return x > 0.f ? x : 0.2f * x; }
static __device__ __forceinline__ uint32_t bfr16(float x) {
  uint32_t u = __float_as_uint(x);
  u += 0x7fffu + ((u >> 16) & 1u);
  return u >> 16;
}
static __device__ __forceinline__ uint32_t pack2(float a, float b) {
  return bfr16(a) | (bfr16(b) << 16);
}
static __device__ __forceinline__ float blo(uint32_t u) { return __uint_as_float(u << 16); }
static __device__ __forceinline__ float bhi(uint32_t u) { return __uint_as_float(u & 0xffff0000u); }

// ---------------- graph prep ----------------
__global__ void hist_kernel(const int* __restrict__ dst, int* __restrict__ indeg) {
  int e = blockIdx.x * 256 + threadIdx.x;
  if (e < N_EDGES) atomicAdd(&indeg[dst[e]], 1);
}

// scan over PADDED degrees (ceil(d/4)*4); 1024 elems/block
__global__ __launch_bounds__(256) void scan_chunks(const int* __restrict__ indeg,
                                                   int* __restrict__ rowstart,
                                                   int* __restrict__ chunksum) {
  int tid = threadIdx.x;
  int base = blockIdx.x * 1024 + tid * 4;
  int4 v;
  if (base + 3 < N_NODES) {
    v = *(const int4*)(indeg + base);
  } else {
    v.x = (base + 0 < N_NODES) ? indeg[base + 0] : 0;
    v.y = (base + 1 < N_NODES) ? indeg[base + 1] : 0;
    v.z = (base + 2 < N_NODES) ? indeg[base + 2] : 0;
    v.w = (base + 3 < N_NODES) ? indeg[base + 3] : 0;
  }
  int px = (v.x + 3) & ~3, py = (v.y + 3) & ~3, pz = (v.z + 3) & ~3, pw = (v.w + 3) & ~3;
  int s = px + py + pz + pw;
  __shared__ int ss[256];
  ss[tid] = s;
  __syncthreads();
  for (int off = 1; off < 256; off <<= 1) {
    int t = (tid >= off) ? ss[tid - off] : 0;
    __syncthreads();
    ss[tid] += t;
    __syncthreads();
  }
  int excl = ss[tid] - s;
  if (base + 0 < N_NODES) rowstart[base + 0] = excl;
  if (base + 1 < N_NODES) rowstart[base + 1] = excl + px;
  if (base + 2 < N_NODES) rowstart[base + 2] = excl + px + py;
  if (base + 3 < N_NODES) rowstart[base + 3] = excl + px + py + pz;
  if (tid == 255) chunksum[blockIdx.x] = ss[255];
}

__global__ void scan_sums(int* __restrict__ chunksum, int nch, int* __restrict__ totalp) {
  __shared__ int ss[128];
  int tid = threadIdx.x;
  int v = (tid < nch) ? chunksum[tid] : 0;
  ss[tid] = v;
  __syncthreads();
  for (int off = 1; off < 128; off <<= 1) {
    int t = (tid >= off) ? ss[tid - off] : 0;
    __syncthreads();
    ss[tid] += t;
    __syncthreads();
  }
  if (tid < nch) chunksum[tid] = ss[tid] - v;  // exclusive
  if (tid == nch - 1) *totalp = ss[tid];       // padded total -> rowstart[N]
}

__global__ void scan_add_dinv(int* __restrict__ rowstart, const int* __restrict__ chunksum,
                              const int* __restrict__ indeg, float* __restrict__ dinv) {
  int i = blockIdx.x * 256 + threadIdx.x;
  if (i < N_NODES) {
    rowstart[i] += chunksum[i >> 10];
    dinv[i] = rsqrtf((float)(indeg[i] + 1));
  }
}

__global__ void scatter_edges(const int* __restrict__ src, const int* __restrict__ dst,
                              const int* __restrict__ rowstart, int* __restrict__ cursor,
                              const float* __restrict__ dinv, int2* __restrict__ csr_sw) {
  int e = blockIdx.x * 256 + threadIdx.x;
  if (e < N_EDGES) {
    int d = dst[e];
    int s = src[e];
    int p = rowstart[d] + atomicAdd(&cursor[d], 1);
    float w = dinv[s] * dinv[d];   // > 0 always (pad sentinel relies on this)
    csr_sw[p] = make_int2(s, __float_as_int(w));
  }
}

// ---------------- prep: cast x to bf16 + pack 4 conv weight matrices ----------------
__global__ void prep_kernel(const float2* __restrict__ x2, uint32_t* __restrict__ xb,
                            const float* __restrict__ W1, const float* __restrict__ W2,
                            const float* __restrict__ W3, const float* __restrict__ W4,
                            unsigned short* __restrict__ Wp1, unsigned short* __restrict__ Wp2,
                            unsigned short* __restrict__ Wp3, unsigned short* __restrict__ Wp4) {
  int b = blockIdx.x;
  if (b < 25000) {
    size_t idx = (size_t)b * 256 + threadIdx.x;
    float2 v = x2[idx];
    xb[idx] = pack2(v.x, v.y);
    return;
  }
  int pb = b - 25000;
  int wsel = pb >> 3;
  int t = (pb & 7) * 256 + threadIdx.x;
  const float* W = (wsel == 0) ? W1 : (wsel == 1) ? W2 : (wsel == 2) ? W3 : W4;
  unsigned short* Wp = (wsel == 0) ? Wp1 : (wsel == 1) ? Wp2 : (wsel == 2) ? Wp3 : Wp4;
  int lane = t & 63;
  int ks = (t >> 6) & 3;
  int nt = t >> 8;
  int c = nt * 16 + (lane & 15);
  int kb = ks * 32 + (lane >> 4) * 8;
#pragma unroll
  for (int i = 0; i < 8; ++i)
    Wp[(size_t)t * 8 + i] = (unsigned short)bfr16(W[(size_t)(kb + i) * 128 + c]);
}

// ---------------- pack MLP weights into MFMA b-frag order ----------------
// layout: loc = nt*(K/32)*64 + ks*64 + lane; elem i: k=ks*32+(lane>>4)*8+i, col=nt*16+(lane&15)
__global__ void pack_mlp(const float* __restrict__ Wh1, const float* __restrict__ Wm0,
                         const float* __restrict__ Wm1, const float* __restrict__ Wo,
                         unsigned short* __restrict__ P1, unsigned short* __restrict__ P2,
                         unsigned short* __restrict__ P3, unsigned short* __restrict__ P4) {
  int t = blockIdx.x * 256 + threadIdx.x;
  const float* W;
  unsigned short* P;
  int K, N, loc;
  if (t < 8192)        { W = Wh1; P = P1; K = 128; N = 512; loc = t; }
  else if (t < 40960)  { W = Wm0; P = P2; K = 512; N = 512; loc = t - 8192; }
  else if (t < 73728)  { W = Wm1; P = P3; K = 512; N = 512; loc = t - 40960; }
  else if (t < 90112)  { W = Wo;  P = P4; K = 512; N = 256; loc = t - 73728; }
  else return;
  int ksn = K >> 5;
  int lane = loc & 63;
  int ks = (loc >> 6) & (ksn - 1);
  int nt = loc / (64 * ksn);
  int c = nt * 16 + (lane & 15);
  int kb = ks * 32 + (lane >> 4) * 8;
#pragma unroll
  for (int i = 0; i < 8; ++i)
    P[(size_t)loc * 8 + i] = (unsigned short)bfr16(W[(size_t)(kb + i) * N + c]);
}

// ---------------- MFMA conv GEMM, optionally fusing BN+ReLU+residual on the A side ------
template <int FUSE>
__global__ __launch_bounds__(256) void gemm_mfma(uint32_t* __restrict__ xbm,
                                                 const float* __restrict__ aggf,
                                                 const float* __restrict__ stats,
                                                 const float* __restrict__ gamma,
                                                 const float* __restrict__ beta,
                                                 const unsigned short* __restrict__ Wp,
                                                 uint32_t* __restrict__ Hb,
                                                 int M) {
  __shared__ float scs[128], bcs[128];
  if (FUSE) {
    int t = threadIdx.x;
    if (t < 128) {
      const float n_inv = 1.f / (float)N_NODES;
      float m = stats[t] * n_inv;
      float v = stats[128 + t] * n_inv - m * m;
      float s = gamma[t] * rsqrtf(v + BN_EPS);
      scs[t] = s;
      bcs[t] = beta[t] - m * s;
    }
    __syncthreads();
  }
  int wave = threadIdx.x >> 6, lane = threadIdx.x & 63;
  int row0 = blockIdx.x * 128 + wave * 32;
  int r = lane & 15, g = lane >> 4;

  f32x4 acc[2][8];
#pragma unroll
  for (int mt = 0; mt < 2; ++mt)
#pragma unroll
    for (int nt = 0; nt < 8; ++nt) acc[mt][nt] = (f32x4){0.f, 0.f, 0.f, 0.f};

  s16x8 a[2][4];
#pragma unroll
  for (int mt = 0; mt < 2; ++mt) {
    int row = row0 + mt * 16 + r;
    bool v = row < M;
    if (FUSE) {
#pragma unroll
      for (int ks = 0; ks < 4; ++ks) {
        int ch = ks * 32 + g * 8;
        s16x8 af = {0, 0, 0, 0, 0, 0, 0, 0};
        if (v) {
          const float4* ap = (const float4*)(aggf + (size_t)row * 128 + ch);
          float4 a0 = ap[0], a1 = ap[1];
          uint4 xo = *(const uint4*)(xbm + (size_t)row * 64 + (ch >> 1));
          float aa[8] = {a0.x, a0.y, a0.z, a0.w, a1.x, a1.y, a1.z, a1.w};
          float xold[8] = {blo(xo.x), bhi(xo.x), blo(xo.y), bhi(xo.y),
                           blo(xo.z), bhi(xo.z), blo(xo.w), bhi(xo.w)};
          uint32_t pk[4];
#pragma unroll
          for (int jj = 0; jj < 4; ++jj) {
            float r0v = fmaxf(fmaf(aa[2 * jj],     scs[ch + 2 * jj],     bcs[ch + 2 * jj]),     0.f) + xold[2 * jj];
            float r1v = fmaxf(fmaf(aa[2 * jj + 1], scs[ch + 2 * jj + 1], bcs[ch + 2 * jj + 1]), 0.f) + xold[2 * jj + 1];
            pk[jj] = pack2(r0v, r1v);
          }
          uint4 st = make_uint4(pk[0], pk[1], pk[2], pk[3]);
          *(uint4*)(xbm + (size_t)row * 64 + (ch >> 1)) = st;
          af = *(s16x8*)&st;
        }
        a[mt][ks] = af;
      }
    } else {
      const unsigned short* ap = (const unsigned short*)xbm + (size_t)row * 128 + g * 8;
#pragma unroll
      for (int ks = 0; ks < 4; ++ks) {
        s16x8 af = {0, 0, 0, 0, 0, 0, 0, 0};
        if (v) af = *(const s16x8*)(ap + ks * 32);
        a[mt][ks] = af;
      }
    }
  }
#pragma unroll
  for (int ks = 0; ks < 4; ++ks) {
#pragma unroll
    for (int nt = 0; nt < 8; ++nt) {
      s16x8 bfr = *(const s16x8*)(Wp + ((size_t)(nt * 4 + ks) * 64 + lane) * 8);
      acc[0][nt] = __builtin_amdgcn_mfma_f32_16x16x32_bf16(a[0][ks], bfr, acc[0][nt], 0, 0, 0);
      acc[1][nt] = __builtin_amdgcn_mfma_f32_16x16x32_bf16(a[1][ks], bfr, acc[1][nt], 0, 0, 0);
    }
  }
#pragma unroll
  for (int mt = 0; mt < 2; ++mt) {
#pragma unroll
    for (int nt = 0; nt < 8; ++nt) {
#pragma unroll
      for (int reg = 0; reg < 4; ++reg) {
        float v0 = acc[mt][nt][reg];
        float v1 = __shfl_xor(v0, 1);
        int row = row0 + mt * 16 + (lane >> 4) * 4 + reg;
        int col = nt * 16 + (lane & 15);
        if (!(lane & 1) && row < M)
          Hb[(size_t)row * 64 + (col >> 1)] = pack2(v0, v1);
      }
    }
  }
}

// ---------------- MLP MFMA GEMM: C = act(A@W + bias); A bf16 [M][K], out bf16 or f32 ----
template <int RELU, int OUTF32>
__global__ __launch_bounds__(256) void gemm_mlp(const uint32_t* __restrict__ Ab,
                                                const unsigned short* __restrict__ Wp,
                                                const float* __restrict__ bias,
                                                void* __restrict__ outp,
                                                int M, int K, int N) {
  int wave = threadIdx.x >> 6, lane = threadIdx.x & 63;
  int row0 = blockIdx.x * 128 + wave * 32;
  int colb = blockIdx.y;
  const unsigned short* A16 = (const unsigned short*)Ab;
  int KS = K >> 5;
  int r = lane & 15, g = lane >> 4;
  f32x4 acc[2][8];
#pragma unroll
  for (int mt = 0; mt < 2; ++mt)
#pragma unroll
    for (int nt = 0; nt < 8; ++nt) acc[mt][nt] = (f32x4){0.f, 0.f, 0.f, 0.f};

  for (int ks = 0; ks < KS; ++ks) {
    s16x8 a[2];
#pragma unroll
    for (int mt = 0; mt < 2; ++mt) {
      int row = row0 + mt * 16 + r;
      s16x8 af = {0, 0, 0, 0, 0, 0, 0, 0};
      if (row < M) af = *(const s16x8*)(A16 + (size_t)row * K + ks * 32 + g * 8);
      a[mt] = af;
    }
#pragma unroll
    for (int ntl = 0; ntl < 8; ++ntl) {
      int ntg = colb * 8 + ntl;
      s16x8 b = *(const s16x8*)(Wp + ((size_t)(ntg * KS + ks) * 64 + lane) * 8);
      acc[0][ntl] = __builtin_amdgcn_mfma_f32_16x16x32_bf16(a[0], b, acc[0][ntl], 0, 0, 0);
      acc[1][ntl] = __builtin_amdgcn_mfma_f32_16x16x32_bf16(a[1], b, acc[1][ntl], 0, 0, 0);
    }
  }
#pragma unroll
  for (int mt = 0; mt < 2; ++mt) {
#pragma unroll
    for (int ntl = 0; ntl < 8; ++ntl) {
#pragma unroll
      for (int reg = 0; reg < 4; ++reg) {
        int row = row0 + mt * 16 + (lane >> 4) * 4 + reg;
        int col = colb * 128 + ntl * 16 + (lane & 15);
        float v0 = acc[mt][ntl][reg] + bias[col];
        if (RELU) v0 = fmaxf(v0, 0.f);
        if (OUTF32) {
          if (row < M) ((float*)outp)[(size_t)row * N + col] = v0;
        } else {
          float v1 = __shfl_xor(v0, 1);
          if (!(lane & 1) && row < M)
            ((uint32_t*)outp)[(size_t)row * (N >> 1) + (col >> 1)] = pack2(v0, v1);
        }
      }
    }
  }
}

// ---------------- unified aggregation: 2 nodes/wave, padded rows, depth-2 row pipeline ----
template <int GAT>
__global__ __launch_bounds__(256) void agg_kernel(const uint2* __restrict__ Hb2,
                                                  const int* __restrict__ rowstart,
                                                  const int2* __restrict__ pack,
                                                  const float* __restrict__ dinv,
                                                  const int* __restrict__ indeg,
                                                  const float* __restrict__ es,
                                                  const float* __restrict__ ed,
                                                  float4* __restrict__ agg4,
                                                  float* __restrict__ stats) {
  const float INVALW = GAT ? -1e30f : 0.0f;
  int tid = threadIdx.x;
  int lane = tid & 63;
  int hl = lane & 31;
  int half = lane >> 5;
  int gw = (blockIdx.x * 256 + tid) >> 6;
  int nw = (gridDim.x * 256) >> 6;
  float s0 = 0, s1 = 0, s2 = 0, s3 = 0, q0 = 0, q1 = 0, q2 = 0, q3 = 0;

#define LOADPK(gq, I0, I1, I2, I3, V0, V1, V2, V3)                        \
  do {                                                                    \
    bool ok = (gq) < G;                                                   \
    int ee = e0 + (gq) * 4;                                               \
    int2 pa = pack[ee], pb = pack[ee + 1], pc = pack[ee + 2], pd = pack[ee + 3]; \
    I0 = ok ? pa.x : 0; V0 = ok ? __int_as_float(pa.y) : INVALW;          \
    I1 = ok ? pb.x : 0; V1 = ok ? __int_as_float(pb.y) : INVALW;          \
    I2 = ok ? pc.x : 0; V2 = ok ? __int_as_float(pc.y) : INVALW;          \
    I3 = ok ? pd.x : 0; V3 = ok ? __int_as_float(pd.y) : INVALW;          \
  } while (0)

  for (int pi = gw; pi < N_NODES / 2; pi += nw) {
    int n = 2 * pi + half;
    int e0 = rowstart[n], e1p = rowstart[n + 1];
    int G = (e1p - e0) >> 2;
    int Gmax = max(G, __shfl_xor(G, 32));
    float edi = 0.f, selfw, fscale = 1.f;
    if (GAT) {
      int len = indeg[n];
      edi = ed[n];
      float wself = __expf(leaky(es[n] + edi));
      float wsum = (hl == 0) ? wself : 0.f;
      for (int e = e0 + hl; e < e0 + len; e += 32)
        wsum += __expf(leaky(__int_as_float(pack[e].y) + edi));
#pragma unroll
      for (int off = 16; off; off >>= 1) wsum += __shfl_xor(wsum, off);
      fscale = 1.f / (wsum + 1e-16f);
      selfw = wself;
    } else {
      float di = dinv[n];
      selfw = di * di;
    }
    uint2 hs = Hb2[(size_t)n * 32 + hl];
    float c0 = blo(hs.x) * selfw, c1 = bhi(hs.x) * selfw;
    float c2 = blo(hs.y) * selfw, c3 = bhi(hs.y) * selfw;

    if (Gmax > 0) {
      int j0, j1, j2, j3;
      float wC0, wC1, wC2, wC3;   // weights for group being consumed
      float wB0, wB1, wB2, wB3;   // group g+1
      float wA0, wA1, wA2, wA3;   // group g+2
      uint2 R00, R01, R02, R03;   // rows group g (ready)
      uint2 R10, R11, R12, R13;   // rows group g+1 (in flight)
      LOADPK(0, j0, j1, j2, j3, wC0, wC1, wC2, wC3);
      R00 = Hb2[(size_t)(unsigned)j0 * 32 + hl];
      R01 = Hb2[(size_t)(unsigned)j1 * 32 + hl];
      R02 = Hb2[(size_t)(unsigned)j2 * 32 + hl];
      R03 = Hb2[(size_t)(unsigned)j3 * 32 + hl];
      LOADPK(1, j0, j1, j2, j3, wB0, wB1, wB2, wB3);
      R10 = Hb2[(size_t)(unsigned)j0 * 32 + hl];
      R11 = Hb2[(size_t)(unsigned)j1 * 32 + hl];
      R12 = Hb2[(size_t)(unsigned)j2 * 32 + hl];
      R13 = Hb2[(size_t)(unsigned)j3 * 32 + hl];
      LOADPK(2, j0, j1, j2, j3, wA0, wA1, wA2, wA3);
      for (int g = 0; g < Gmax; ++g) {
        uint2 R20, R21, R22, R23;
        if (g + 2 < Gmax) {   // uniform
          R20 = Hb2[(size_t)(unsigned)j0 * 32 + hl];
          R21 = Hb2[(size_t)(unsigned)j1 * 32 + hl];
          R22 = Hb2[(size_t)(unsigned)j2 * 32 + hl];
          R23 = Hb2[(size_t)(unsigned)j3 * 32 + hl];
        }
        int k0, k1, k2, k3;
        float wN0, wN1, wN2, wN3;
        if (g + 3 < Gmax) {   // uniform
          LOADPK(g + 3, k0, k1, k2, k3, wN0, wN1, wN2, wN3);
        } else {
          k0 = k1 = k2 = k3 = 0;
          wN0 = wN1 = wN2 = wN3 = INVALW;
        }
        float f0, f1, f2, f3;
        if (GAT) {
          f0 = __expf(leaky(wC0 + edi)); f1 = __expf(leaky(wC1 + edi));
          f2 = __expf(leaky(wC2 + edi)); f3 = __expf(leaky(wC3 + edi));
        } else {
          f0 = wC0; f1 = wC1; f2 = wC2; f3 = wC3;
        }
        c0 = fmaf(blo(R00.x), f0, c0); c1 = fmaf(bhi(R00.x), f0, c1);
        c2 = fmaf(blo(R00.y), f0, c2); c3 = fmaf(bhi(R00.y), f0, c3);
        c0 = fmaf(blo(R01.x), f1, c0); c1 = fmaf(bhi(R01.x), f1, c1);
        c2 = fmaf(blo(R01.y), f1, c2); c3 = fmaf(bhi(R01.y), f1, c3);
        c0 = fmaf(blo(R02.x), f2, c0); c1 = fmaf(bhi(R02.x), f2, c1);
        c2 = fmaf(blo(R02.y), f2, c2); c3 = fmaf(bhi(R02.y), f2, c3);
        c0 = fmaf(blo(R03.x), f3, c0); c1 = fmaf(bhi(R03.x), f3, c1);
        c2 = fmaf(blo(R03.y), f3, c2); c3 = fmaf(bhi(R03.y), f3, c3);
        R00 = R10; R01 = R11; R02 = R12; R03 = R13;
        R10 = R20; R11 = R21; R12 = R22; R13 = R23;
        wC0 = wB0; wC1 = wB1; wC2 = wB2; wC3 = wB3;
        wB0 = wA0; wB1 = wA1; wB2 = wA2; wB3 = wA3;
        wA0 = wN0; wA1 = wN1; wA2 = wN2; wA3 = wN3;
        j0 = k0; j1 = k1; j2 = k2; j3 = k3;
      }
    }
    if (GAT) { c0 *= fscale; c1 *= fscale; c2 *= fscale; c3 *= fscale; }
    agg4[(size_t)n * 32 + hl] = make_float4(c0, c1, c2, c3);
    s0 += c0; s1 += c1; s2 += c2; s3 += c3;
    q0 += c0 * c0; q1 += c1 * c1; q2 += c2 * c2; q3 += c3 * c3;
  }
#undef LOADPK
  s0 += __shfl_xor(s0, 32); s1 += __shfl_xor(s1, 32);
  s2 += __shfl_xor(s2, 32); s3 += __shfl_xor(s3, 32);
  q0 += __shfl_xor(q0, 32); q1 += __shfl_xor(q1, 32);
  q2 += __shfl_xor(q2, 32); q3 += __shfl_xor(q3, 32);
  __shared__ float red[4][128];
  int w = tid >> 6;
  if (half == 0) {
    red[w][4 * hl + 0] = s0; red[w][4 * hl + 1] = s1;
    red[w][4 * hl + 2] = s2; red[w][4 * hl + 3] = s3;
  }
  __syncthreads();
  if (w == 0) {
    float a = red[0][2 * lane] + red[1][2 * lane] + red[2][2 * lane] + red[3][2 * lane];
    float b = red[0][2 * lane + 1] + red[1][2 * lane + 1] + red[2][2 * lane + 1] + red[3][2 * lane + 1];
    atomicAdd(&stats[2 * lane], a);
    atomicAdd(&stats[2 * lane + 1], b);
  }
  __syncthreads();
  if (half == 0) {
    red[w][4 * hl + 0] = q0; red[w][4 * hl + 1] = q1;
    red[w][4 * hl + 2] = q2; red[w][4 * hl + 3] = q3;
  }
  __syncthreads();
  if (w == 0) {
    float a = red[0][2 * lane] + red[1][2 * lane] + red[2][2 * lane] + red[3][2 * lane];
    float b = red[0][2 * lane + 1] + red[1][2 * lane + 1] + red[2][2 * lane + 1] + red[3][2 * lane + 1];
    atomicAdd(&stats[128 + 2 * lane], a);
    atomicAdd(&stats[128 + 2 * lane + 1], b);
  }
}

// ---------------- es/ed for GAT ----------------
__global__ __launch_bounds__(256) void compute_esed(const uint32_t* __restrict__ Hb,
                                                    const float* __restrict__ asrc,
                                                    const float* __restrict__ adst,
                                                    float* __restrict__ es, float* __restrict__ ed) {
  int lane = threadIdx.x & 63;
  int gwave = (blockIdx.x * 256 + threadIdx.x) >> 6;
  if (gwave >= N_NODES) return;
  float2 av = ((const float2*)asrc)[lane];
  float2 dv = ((const float2*)adst)[lane];
  uint32_t hv = Hb[(size_t)gwave * 64 + lane];
  float hx = blo(hv), hy = bhi(hv);
  float e_s = hx * av.x + hy * av.y;
  float e_d = hx * dv.x + hy * dv.y;
  for (int off = 32; off; off >>= 1) {
    e_s += __shfl_down(e_s, off);
    e_d += __shfl_down(e_d, off);
  }
  if (lane == 0) { es[gwave] = e_s; ed[gwave] = e_d; }
}

// overwrite pack.y: pads (y==0, only possible for pad slots) -> -1e30 sentinel; else es[src]
__global__ void gat_pack_kernel(int2* __restrict__ sw, const float* __restrict__ es) {
  int e = blockIdx.x * 256 + threadIdx.x;
  if (e < CSR_CAP) {
    int2 v = sw[e];
    v.y = (v.y == 0) ? __float_as_int(-1e30f) : __float_as_int(es[v.x]);
    sw[e] = v;
  }
}

// ---------------- pooling with fused BN+ReLU+residual of last layer; bf16 out ----------------
__global__ void graph_starts(const int* __restrict__ batch, int* __restrict__ gstart) {
  int n = blockIdx.x * 256 + threadIdx.x;
  if (n >= N_NODES) return;
  int b = batch[n];
  int bp = (n == 0) ? -1 : batch[n - 1];
  for (int g = bp + 1; g <= b; ++g) gstart[g] = n;
  if (n == N_NODES - 1) {
    for (int g = b + 1; g <= BG; ++g) gstart[g] = N_NODES;
  }
}

__global__ __launch_bounds__(256) void pool_bn(const float* __restrict__ aggf,
                                               const uint32_t* __restrict__ xb,
                                               const float* __restrict__ stats,
                                               const float* __restrict__ gamma,
                                               const float* __restrict__ beta,
                                               const int* __restrict__ gstart,
                                               uint32_t* __restrict__ pooledb) {
  int g = blockIdx.x;
  int c = threadIdx.x & 127;
  int half = threadIdx.x >> 7;
  const float n_inv = 1.f / (float)N_NODES;
  float m = stats[c] * n_inv;
  float v = stats[128 + c] * n_inv - m * m;
  float sc = gamma[c] * rsqrtf(v + BN_EPS);
  float bc = beta[c] - m * sc;
  int s = gstart[g], e = gstart[g + 1];
  float acc = 0.f;
  for (int n = s + half; n < e; n += 2) {
    float a = aggf[(size_t)n * 128 + c];
    uint32_t u = xb[(size_t)n * 64 + (c >> 1)];
    float xo = (c & 1) ? bhi(u) : blo(u);
    acc += fmaxf(fmaf(a, sc, bc), 0.f) + xo;
  }
  __shared__ float red[256];
  __shared__ float fin[128];
  red[threadIdx.x] = acc;
  __syncthreads();
  if (half == 0) {
    float vsum = red[c] + red[128 + c];
    int cnt = e - s;
    fin[c] = vsum / fmaxf((float)cnt, 1.f);
  }
  __syncthreads();
  if (half == 0 && !(c & 1))
    pooledb[(size_t)g * 64 + (c >> 1)] = pack2(fin[c], fin[c + 1]);
}

// ---------------- host launch ----------------
extern "C" void kernel_launch(void* const* d_in, const int* in_sizes, int n_in,
                              void* d_out, int out_size, void* d_ws, size_t ws_size,
                              hipStream_t stream) {
  const float* x_in  = (const float*)d_in[0];
  const int*   eidx  = (const int*)d_in[1];
  const int*   batch = (const int*)d_in[2];
  const float* W1 = (const float*)d_in[3];
  const float* g1 = (const float*)d_in[5];
  const float* be1 = (const float*)d_in[6];
  const float* W2 = (const float*)d_in[7];
  const float* g2 = (const float*)d_in[9];
  const float* be2 = (const float*)d_in[10];
  const float* W3 = (const float*)d_in[11];
  const float* g3 = (const float*)d_in[13];
  const float* be3 = (const float*)d_in[14];
  const float* Wa = (const float*)d_in[15];
  const float* asrc = (const float*)d_in[16];
  const float* adst = (const float*)d_in[17];
  const float* ga = (const float*)d_in[19];
  const float* bea = (const float*)d_in[20];
  const float* Wh1 = (const float*)d_in[21];
  const float* bh1 = (const float*)d_in[22];
  const float* Wm0 = (const float*)d_in[23];
  const float* bm0 = (const float*)d_in[24];
  const float* Wm1 = (const float*)d_in[25];
  const float* bm1 = (const float*)d_in[26];
  const float* Wo = (const float*)d_in[27];
  const float* bo = (const float*)d_in[28];

  const int* src = eidx;
  const int* dst = eidx + N_EDGES;

  char* p = (char*)d_ws;
  auto alloc = [&](size_t bytes) {
    char* r = p;
    p += (bytes + 255) & ~(size_t)255;
    return r;
  };
  uint32_t* Hb     = (uint32_t*)alloc((size_t)N_NODES * 64 * 4);
  uint32_t* xb     = (uint32_t*)alloc((size_t)N_NODES * 64 * 4);
  float* agg       = (float*)alloc((size_t)N_NODES * CCH * 4);
  int2*  csr_sw    = (int2*)alloc((size_t)CSR_CAP * 8);
  int*   rowstart  = (int*)alloc((size_t)(N_NODES + 1) * 4);
  int*   indeg     = (int*)alloc((size_t)2 * N_NODES * 4);
  int*   cursor    = indeg + N_NODES;
  float* dinv      = (float*)alloc((size_t)N_NODES * 4);
  float* es        = (float*)alloc((size_t)N_NODES * 4);
  float* ed        = (float*)alloc((size_t)N_NODES * 4);
  int*   chunksum  = (int*)alloc(128 * 4);
  float* stats     = (float*)alloc(4 * 256 * 4);
  int*   gstart    = (int*)alloc((BG + 1) * 4);
  uint32_t* pooledb = (uint32_t*)alloc((size_t)BG * 64 * 4);
  uint32_t* m1b    = (uint32_t*)alloc((size_t)BG * (NHID / 2) * 4);
  uint32_t* m2b    = (uint32_t*)alloc((size_t)BG * (NHID / 2) * 4);
  unsigned short* Wp1 = (unsigned short*)alloc(2048 * 8 * 2);
  unsigned short* Wp2 = (unsigned short*)alloc(2048 * 8 * 2);
  unsigned short* Wp3 = (unsigned short*)alloc(2048 * 8 * 2);
  unsigned short* Wp4 = (unsigned short*)alloc(2048 * 8 * 2);
  unsigned short* P1 = (unsigned short*)alloc((size_t)8192 * 8 * 2);
  unsigned short* P2 = (unsigned short*)alloc((size_t)32768 * 8 * 2);
  unsigned short* P3 = (unsigned short*)alloc((size_t)32768 * 8 * 2);
  unsigned short* P4 = (unsigned short*)alloc((size_t)16384 * 8 * 2);

  hipMemsetAsync(indeg, 0, (size_t)2 * N_NODES * 4, stream);
  hipMemsetAsync(stats, 0, 4 * 256 * 4, stream);
  hipMemsetAsync(csr_sw, 0, (size_t)CSR_CAP * 8, stream);

  // CSR build (padded rows)
  hist_kernel<<<(N_EDGES + 255) / 256, 256, 0, stream>>>(dst, indeg);
  scan_chunks<<<98, 256, 0, stream>>>(indeg, rowstart, chunksum);
  scan_sums<<<1, 128, 0, stream>>>(chunksum, 98, rowstart + N_NODES);
  scan_add_dinv<<<(N_NODES + 255) / 256, 256, 0, stream>>>(rowstart, chunksum, indeg, dinv);
  scatter_edges<<<(N_EDGES + 255) / 256, 256, 0, stream>>>(src, dst, rowstart, cursor, dinv, csr_sw);

  // prep: cast x + pack conv weights + pack MLP weights
  prep_kernel<<<25000 + 32, 256, 0, stream>>>((const float2*)x_in, xb, W1, W2, W3, Wa,
                                              Wp1, Wp2, Wp3, Wp4);
  pack_mlp<<<352, 256, 0, stream>>>(Wh1, Wm0, Wm1, Wo, P1, P2, P3, P4);

  const int gemm_blocks_m = (N_NODES + 127) / 128;  // 782
  const int AGG_BLOCKS = 2048;

  // layer 1
  gemm_mfma<0><<<gemm_blocks_m, 256, 0, stream>>>(xb, nullptr, nullptr, nullptr, nullptr,
                                                  Wp1, Hb, N_NODES);
  agg_kernel<0><<<AGG_BLOCKS, 256, 0, stream>>>((const uint2*)Hb, rowstart, csr_sw, dinv,
                                                indeg, nullptr, nullptr, (float4*)agg, stats + 0 * 256);
  // layer 2 (fuse BN1)
  gemm_mfma<1><<<gemm_blocks_m, 256, 0, stream>>>(xb, agg, stats + 0 * 256, g1, be1,
                                                  Wp2, Hb, N_NODES);
  agg_kernel<0><<<AGG_BLOCKS, 256, 0, stream>>>((const uint2*)Hb, rowstart, csr_sw, dinv,
                                                indeg, nullptr, nullptr, (float4*)agg, stats + 1 * 256);
  // layer 3 (fuse BN2)
  gemm_mfma<1><<<gemm_blocks_m, 256, 0, stream>>>(xb, agg, stats + 1 * 256, g2, be2,
                                                  Wp3, Hb, N_NODES);
  agg_kernel<0><<<AGG_BLOCKS, 256, 0, stream>>>((const uint2*)Hb, rowstart, csr_sw, dinv,
                                                indeg, nullptr, nullptr, (float4*)agg, stats + 2 * 256);
  // layer 4 = GAT (fuse BN3)
  gemm_mfma<1><<<gemm_blocks_m, 256, 0, stream>>>(xb, agg, stats + 2 * 256, g3, be3,
                                                  Wp4, Hb, N_NODES);
  compute_esed<<<(N_NODES + 3) / 4, 256, 0, stream>>>(Hb, asrc, adst, es, ed);
  gat_pack_kernel<<<(CSR_CAP + 255) / 256, 256, 0, stream>>>(csr_sw, es);
  agg_kernel<1><<<AGG_BLOCKS, 256, 0, stream>>>((const uint2*)Hb, rowstart, csr_sw, nullptr,
                                                indeg, es, ed, (float4*)agg, stats + 3 * 256);

  // pooling (fuses BN4), bf16 out
  graph_starts<<<(N_NODES + 255) / 256, 256, 0, stream>>>(batch, gstart);
  pool_bn<<<BG, 256, 0, stream>>>(agg, xb, stats + 3 * 256, ga, bea, gstart, pooledb);

  // MLP head (MFMA bf16)
  gemm_mlp<1, 0><<<dim3(4, 4), 256, 0, stream>>>(pooledb, P1, bh1, m1b, BG, CCH, NHID);
  gemm_mlp<1, 0><<<dim3(4, 4), 256, 0, stream>>>(m1b, P2, bm0, m2b, BG, NHID, NHID);
  gemm_mlp<1, 0><<<dim3(4, 4), 256, 0, stream>>>(m2b, P3, bm1, m1b, BG, NHID, NHID);
  gemm_mlp<0, 1><<<dim3(4, 2), 256, 0, stream>>>(m1b, P4, bo, d_out, BG, NHID, NOUT);
}

// Round 8
// 1027.887 us; speedup vs baseline: 1.1686x; 1.0123x over previous
//
#include <hip/hip_runtime.h>
#include <hip/hip_fp16.h>

// Problem constants (match reference)
#define N_NODES 100000
#define N_EDGES 1600000
#define CCH     128
#define BG      512
#define NHID    512
#define NOUT    256
#define BN_EPS  1e-5f
// padded CSR capacity: sum ceil(d/4)*4 <= E + 3N, +128 tail pad
#define CSR_CAP (N_EDGES + 4 * N_NODES + 128)

typedef __attribute__((ext_vector_type(8))) short s16x8;
typedef __attribute__((ext_vector_type(4))) float f32x4;

static __device__ __forceinline__ float leaky(float x) { return x > 0.f ? x : 0.2f * x; }
static __device__ __forceinline__ uint32_t bfr16(float x) {
  uint32_t u = __float_as_uint(x);
  u += 0x7fffu + ((u >> 16) & 1u);
  return u >> 16;
}
static __device__ __forceinline__ uint32_t pack2(float a, float b) {
  return bfr16(a) | (bfr16(b) << 16);
}
static __device__ __forceinline__ float blo(uint32_t u) { return __uint_as_float(u << 16); }
static __device__ __forceinline__ float bhi(uint32_t u) { return __uint_as_float(u & 0xffff0000u); }
// fp16 pair helpers (agg payload: 4x less rounding noise than bf16, same 16 bits)
static __device__ __forceinline__ uint32_t packh2(float a, float b) {
  __half2 h;
  h.x = __float2half(a);
  h.y = __float2half(b);
  return *reinterpret_cast<uint32_t*>(&h);
}
static __device__ __forceinline__ float hlo(uint32_t u) {
  __half2 h = *reinterpret_cast<__half2*>(&u);
  return __half2float(h.x);
}
static __device__ __forceinline__ float hhi(uint32_t u) {
  __half2 h = *reinterpret_cast<__half2*>(&u);
  return __half2float(h.y);
}

// ---------------- graph prep ----------------
__global__ void hist_kernel(const int* __restrict__ dst, int* __restrict__ indeg) {
  int e = blockIdx.x * 256 + threadIdx.x;
  if (e < N_EDGES) atomicAdd(&indeg[dst[e]], 1);
}

// scan over PADDED degrees (ceil(d/4)*4); 1024 elems/block
__global__ __launch_bounds__(256) void scan_chunks(const int* __restrict__ indeg,
                                                   int* __restrict__ rowstart,
                                                   int* __restrict__ chunksum) {
  int tid = threadIdx.x;
  int base = blockIdx.x * 1024 + tid * 4;
  int4 v;
  if (base + 3 < N_NODES) {
    v = *(const int4*)(indeg + base);
  } else {
    v.x = (base + 0 < N_NODES) ? indeg[base + 0] : 0;
    v.y = (base + 1 < N_NODES) ? indeg[base + 1] : 0;
    v.z = (base + 2 < N_NODES) ? indeg[base + 2] : 0;
    v.w = (base + 3 < N_NODES) ? indeg[base + 3] : 0;
  }
  int px = (v.x + 3) & ~3, py = (v.y + 3) & ~3, pz = (v.z + 3) & ~3, pw = (v.w + 3) & ~3;
  int s = px + py + pz + pw;
  __shared__ int ss[256];
  ss[tid] = s;
  __syncthreads();
  for (int off = 1; off < 256; off <<= 1) {
    int t = (tid >= off) ? ss[tid - off] : 0;
    __syncthreads();
    ss[tid] += t;
    __syncthreads();
  }
  int excl = ss[tid] - s;
  if (base + 0 < N_NODES) rowstart[base + 0] = excl;
  if (base + 1 < N_NODES) rowstart[base + 1] = excl + px;
  if (base + 2 < N_NODES) rowstart[base + 2] = excl + px + py;
  if (base + 3 < N_NODES) rowstart[base + 3] = excl + px + py + pz;
  if (tid == 255) chunksum[blockIdx.x] = ss[255];
}

__global__ void scan_sums(int* __restrict__ chunksum, int nch, int* __restrict__ totalp) {
  __shared__ int ss[128];
  int tid = threadIdx.x;
  int v = (tid < nch) ? chunksum[tid] : 0;
  ss[tid] = v;
  __syncthreads();
  for (int off = 1; off < 128; off <<= 1) {
    int t = (tid >= off) ? ss[tid - off] : 0;
    __syncthreads();
    ss[tid] += t;
    __syncthreads();
  }
  if (tid < nch) chunksum[tid] = ss[tid] - v;  // exclusive
  if (tid == nch - 1) *totalp = ss[tid];       // padded total -> rowstart[N]
}

__global__ void scan_add_dinv(int* __restrict__ rowstart, const int* __restrict__ chunksum,
                              const int* __restrict__ indeg, float* __restrict__ dinv) {
  int i = blockIdx.x * 256 + threadIdx.x;
  if (i < N_NODES) {
    rowstart[i] += chunksum[i >> 10];
    dinv[i] = rsqrtf((float)(indeg[i] + 1));
  }
}

__global__ void scatter_edges(const int* __restrict__ src, const int* __restrict__ dst,
                              const int* __restrict__ rowstart, int* __restrict__ cursor,
                              const float* __restrict__ dinv, int2* __restrict__ csr_sw) {
  int e = blockIdx.x * 256 + threadIdx.x;
  if (e < N_EDGES) {
    int d = dst[e];
    int s = src[e];
    int p = rowstart[d] + atomicAdd(&cursor[d], 1);
    float w = dinv[s] * dinv[d];   // > 0 always (pad sentinel relies on this)
    csr_sw[p] = make_int2(s, __float_as_int(w));
  }
}

// ---------------- prep: cast x to bf16 + pack 4 conv weight matrices ----------------
__global__ void prep_kernel(const float2* __restrict__ x2, uint32_t* __restrict__ xb,
                            const float* __restrict__ W1, const float* __restrict__ W2,
                            const float* __restrict__ W3, const float* __restrict__ W4,
                            unsigned short* __restrict__ Wp1, unsigned short* __restrict__ Wp2,
                            unsigned short* __restrict__ Wp3, unsigned short* __restrict__ Wp4) {
  int b = blockIdx.x;
  if (b < 25000) {
    size_t idx = (size_t)b * 256 + threadIdx.x;
    float2 v = x2[idx];
    xb[idx] = pack2(v.x, v.y);
    return;
  }
  int pb = b - 25000;
  int wsel = pb >> 3;
  int t = (pb & 7) * 256 + threadIdx.x;
  const float* W = (wsel == 0) ? W1 : (wsel == 1) ? W2 : (wsel == 2) ? W3 : W4;
  unsigned short* Wp = (wsel == 0) ? Wp1 : (wsel == 1) ? Wp2 : (wsel == 2) ? Wp3 : Wp4;
  int lane = t & 63;
  int ks = (t >> 6) & 3;
  int nt = t >> 8;
  int c = nt * 16 + (lane & 15);
  int kb = ks * 32 + (lane >> 4) * 8;
#pragma unroll
  for (int i = 0; i < 8; ++i)
    Wp[(size_t)t * 8 + i] = (unsigned short)bfr16(W[(size_t)(kb + i) * 128 + c]);
}

// ---------------- pack MLP weights into MFMA b-frag order ----------------
__global__ void pack_mlp(const float* __restrict__ Wh1, const float* __restrict__ Wm0,
                         const float* __restrict__ Wm1, const float* __restrict__ Wo,
                         unsigned short* __restrict__ P1, unsigned short* __restrict__ P2,
                         unsigned short* __restrict__ P3, unsigned short* __restrict__ P4) {
  int t = blockIdx.x * 256 + threadIdx.x;
  const float* W;
  unsigned short* P;
  int K, N, loc;
  if (t < 8192)        { W = Wh1; P = P1; K = 128; N = 512; loc = t; }
  else if (t < 40960)  { W = Wm0; P = P2; K = 512; N = 512; loc = t - 8192; }
  else if (t < 73728)  { W = Wm1; P = P3; K = 512; N = 512; loc = t - 40960; }
  else if (t < 90112)  { W = Wo;  P = P4; K = 512; N = 256; loc = t - 73728; }
  else return;
  int ksn = K >> 5;
  int lane = loc & 63;
  int ks = (loc >> 6) & (ksn - 1);
  int nt = loc / (64 * ksn);
  int c = nt * 16 + (lane & 15);
  int kb = ks * 32 + (lane >> 4) * 8;
#pragma unroll
  for (int i = 0; i < 8; ++i)
    P[(size_t)loc * 8 + i] = (unsigned short)bfr16(W[(size_t)(kb + i) * N + c]);
}

// ---------------- MFMA conv GEMM, optionally fusing BN+ReLU+residual on the A side ------
// FUSE=1: xnew = relu(bn(agg_fp16)) + xold; writes xnew back to xbm AND uses it as A.
template <int FUSE>
__global__ __launch_bounds__(256) void gemm_mfma(uint32_t* __restrict__ xbm,
                                                 const uint32_t* __restrict__ aggb,   // [M][64] fp16 pairs
                                                 const float* __restrict__ stats,
                                                 const float* __restrict__ gamma,
                                                 const float* __restrict__ beta,
                                                 const unsigned short* __restrict__ Wp,
                                                 uint32_t* __restrict__ Hb,
                                                 int M) {
  __shared__ float scs[128], bcs[128];
  if (FUSE) {
    int t = threadIdx.x;
    if (t < 128) {
      const float n_inv = 1.f / (float)N_NODES;
      float m = stats[t] * n_inv;
      float v = stats[128 + t] * n_inv - m * m;
      float s = gamma[t] * rsqrtf(v + BN_EPS);
      scs[t] = s;
      bcs[t] = beta[t] - m * s;
    }
    __syncthreads();
  }
  int wave = threadIdx.x >> 6, lane = threadIdx.x & 63;
  int row0 = blockIdx.x * 128 + wave * 32;
  int r = lane & 15, g = lane >> 4;

  f32x4 acc[2][8];
#pragma unroll
  for (int mt = 0; mt < 2; ++mt)
#pragma unroll
    for (int nt = 0; nt < 8; ++nt) acc[mt][nt] = (f32x4){0.f, 0.f, 0.f, 0.f};

  s16x8 a[2][4];
#pragma unroll
  for (int mt = 0; mt < 2; ++mt) {
    int row = row0 + mt * 16 + r;
    bool v = row < M;
    if (FUSE) {
#pragma unroll
      for (int ks = 0; ks < 4; ++ks) {
        int ch = ks * 32 + g * 8;
        s16x8 af = {0, 0, 0, 0, 0, 0, 0, 0};
        if (v) {
          uint4 av4 = *(const uint4*)(aggb + (size_t)row * 64 + (ch >> 1));
          uint4 xo = *(const uint4*)(xbm + (size_t)row * 64 + (ch >> 1));
          float aa[8] = {hlo(av4.x), hhi(av4.x), hlo(av4.y), hhi(av4.y),
                         hlo(av4.z), hhi(av4.z), hlo(av4.w), hhi(av4.w)};
          float xold[8] = {blo(xo.x), bhi(xo.x), blo(xo.y), bhi(xo.y),
                           blo(xo.z), bhi(xo.z), blo(xo.w), bhi(xo.w)};
          uint32_t pk[4];
#pragma unroll
          for (int jj = 0; jj < 4; ++jj) {
            float r0v = fmaxf(fmaf(aa[2 * jj],     scs[ch + 2 * jj],     bcs[ch + 2 * jj]),     0.f) + xold[2 * jj];
            float r1v = fmaxf(fmaf(aa[2 * jj + 1], scs[ch + 2 * jj + 1], bcs[ch + 2 * jj + 1]), 0.f) + xold[2 * jj + 1];
            pk[jj] = pack2(r0v, r1v);
          }
          uint4 st = make_uint4(pk[0], pk[1], pk[2], pk[3]);
          *(uint4*)(xbm + (size_t)row * 64 + (ch >> 1)) = st;
          af = *(s16x8*)&st;
        }
        a[mt][ks] = af;
      }
    } else {
      const unsigned short* ap = (const unsigned short*)xbm + (size_t)row * 128 + g * 8;
#pragma unroll
      for (int ks = 0; ks < 4; ++ks) {
        s16x8 af = {0, 0, 0, 0, 0, 0, 0, 0};
        if (v) af = *(const s16x8*)(ap + ks * 32);
        a[mt][ks] = af;
      }
    }
  }
#pragma unroll
  for (int ks = 0; ks < 4; ++ks) {
#pragma unroll
    for (int nt = 0; nt < 8; ++nt) {
      s16x8 bfr = *(const s16x8*)(Wp + ((size_t)(nt * 4 + ks) * 64 + lane) * 8);
      acc[0][nt] = __builtin_amdgcn_mfma_f32_16x16x32_bf16(a[0][ks], bfr, acc[0][nt], 0, 0, 0);
      acc[1][nt] = __builtin_amdgcn_mfma_f32_16x16x32_bf16(a[1][ks], bfr, acc[1][nt], 0, 0, 0);
    }
  }
#pragma unroll
  for (int mt = 0; mt < 2; ++mt) {
#pragma unroll
    for (int nt = 0; nt < 8; ++nt) {
#pragma unroll
      for (int reg = 0; reg < 4; ++reg) {
        float v0 = acc[mt][nt][reg];
        float v1 = __shfl_xor(v0, 1);
        int row = row0 + mt * 16 + (lane >> 4) * 4 + reg;
        int col = nt * 16 + (lane & 15);
        if (!(lane & 1) && row < M)
          Hb[(size_t)row * 64 + (col >> 1)] = pack2(v0, v1);
      }
    }
  }
}

// ---------------- MLP MFMA GEMM: C = act(A@W + bias); A bf16 [M][K], out bf16 or f32 ----
template <int RELU, int OUTF32>
__global__ __launch_bounds__(256) void gemm_mlp(const uint32_t* __restrict__ Ab,
                                                const unsigned short* __restrict__ Wp,
                                                const float* __restrict__ bias,
                                                void* __restrict__ outp,
                                                int M, int K, int N) {
  int wave = threadIdx.x >> 6, lane = threadIdx.x & 63;
  int row0 = blockIdx.x * 128 + wave * 32;
  int colb = blockIdx.y;
  const unsigned short* A16 = (const unsigned short*)Ab;
  int KS = K >> 5;
  int r = lane & 15, g = lane >> 4;
  f32x4 acc[2][8];
#pragma unroll
  for (int mt = 0; mt < 2; ++mt)
#pragma unroll
    for (int nt = 0; nt < 8; ++nt) acc[mt][nt] = (f32x4){0.f, 0.f, 0.f, 0.f};

  for (int ks = 0; ks < KS; ++ks) {
    s16x8 a[2];
#pragma unroll
    for (int mt = 0; mt < 2; ++mt) {
      int row = row0 + mt * 16 + r;
      s16x8 af = {0, 0, 0, 0, 0, 0, 0, 0};
      if (row < M) af = *(const s16x8*)(A16 + (size_t)row * K + ks * 32 + g * 8);
      a[mt] = af;
    }
#pragma unroll
    for (int ntl = 0; ntl < 8; ++ntl) {
      int ntg = colb * 8 + ntl;
      s16x8 b = *(const s16x8*)(Wp + ((size_t)(ntg * KS + ks) * 64 + lane) * 8);
      acc[0][ntl] = __builtin_amdgcn_mfma_f32_16x16x32_bf16(a[0], b, acc[0][ntl], 0, 0, 0);
      acc[1][ntl] = __builtin_amdgcn_mfma_f32_16x16x32_bf16(a[1], b, acc[1][ntl], 0, 0, 0);
    }
  }
#pragma unroll
  for (int mt = 0; mt < 2; ++mt) {
#pragma unroll
    for (int ntl = 0; ntl < 8; ++ntl) {
#pragma unroll
      for (int reg = 0; reg < 4; ++reg) {
        int row = row0 + mt * 16 + (lane >> 4) * 4 + reg;
        int col = colb * 128 + ntl * 16 + (lane & 15);
        float v0 = acc[mt][ntl][reg] + bias[col];
        if (RELU) v0 = fmaxf(v0, 0.f);
        if (OUTF32) {
          if (row < M) ((float*)outp)[(size_t)row * N + col] = v0;
        } else {
          float v1 = __shfl_xor(v0, 1);
          if (!(lane & 1) && row < M)
            ((uint32_t*)outp)[(size_t)row * (N >> 1) + (col >> 1)] = pack2(v0, v1);
        }
      }
    }
  }
}

// ---------------- unified aggregation: 2 nodes/wave, padded rows, depth-2 row pipeline ----
// Output packed fp16 pairs [M][64] words.
template <int GAT>
__global__ __launch_bounds__(256) void agg_kernel(const uint2* __restrict__ Hb2,
                                                  const int* __restrict__ rowstart,
                                                  const int2* __restrict__ pack,
                                                  const float* __restrict__ dinv,
                                                  const int* __restrict__ indeg,
                                                  const float* __restrict__ es,
                                                  const float* __restrict__ ed,
                                                  uint32_t* __restrict__ aggb,
                                                  float* __restrict__ stats) {
  const float INVALW = GAT ? -1e30f : 0.0f;
  int tid = threadIdx.x;
  int lane = tid & 63;
  int hl = lane & 31;
  int half = lane >> 5;
  int gw = (blockIdx.x * 256 + tid) >> 6;
  int nw = (gridDim.x * 256) >> 6;
  float s0 = 0, s1 = 0, s2 = 0, s3 = 0, q0 = 0, q1 = 0, q2 = 0, q3 = 0;

#define LOADPK(gq, I0, I1, I2, I3, V0, V1, V2, V3)                        \
  do {                                                                    \
    bool ok = (gq) < G;                                                   \
    int ee = e0 + (gq) * 4;                                               \
    int2 pa = pack[ee], pb = pack[ee + 1], pc = pack[ee + 2], pd = pack[ee + 3]; \
    I0 = ok ? pa.x : 0; V0 = ok ? __int_as_float(pa.y) : INVALW;          \
    I1 = ok ? pb.x : 0; V1 = ok ? __int_as_float(pb.y) : INVALW;          \
    I2 = ok ? pc.x : 0; V2 = ok ? __int_as_float(pc.y) : INVALW;          \
    I3 = ok ? pd.x : 0; V3 = ok ? __int_as_float(pd.y) : INVALW;          \
  } while (0)

  for (int pi = gw; pi < N_NODES / 2; pi += nw) {
    int n = 2 * pi + half;
    int e0 = rowstart[n], e1p = rowstart[n + 1];
    int G = (e1p - e0) >> 2;
    int Gmax = max(G, __shfl_xor(G, 32));
    float edi = 0.f, selfw, fscale = 1.f;
    if (GAT) {
      int len = indeg[n];
      edi = ed[n];
      float wself = __expf(leaky(es[n] + edi));
      float wsum = (hl == 0) ? wself : 0.f;
      for (int e = e0 + hl; e < e0 + len; e += 32)
        wsum += __expf(leaky(__int_as_float(pack[e].y) + edi));
#pragma unroll
      for (int off = 16; off; off >>= 1) wsum += __shfl_xor(wsum, off);
      fscale = 1.f / (wsum + 1e-16f);
      selfw = wself;
    } else {
      float di = dinv[n];
      selfw = di * di;
    }
    uint2 hs = Hb2[(size_t)n * 32 + hl];
    float c0 = blo(hs.x) * selfw, c1 = bhi(hs.x) * selfw;
    float c2 = blo(hs.y) * selfw, c3 = bhi(hs.y) * selfw;

    if (Gmax > 0) {
      int j0, j1, j2, j3;
      float wC0, wC1, wC2, wC3;
      float wB0, wB1, wB2, wB3;
      float wA0, wA1, wA2, wA3;
      uint2 R00, R01, R02, R03;
      uint2 R10, R11, R12, R13;
      LOADPK(0, j0, j1, j2, j3, wC0, wC1, wC2, wC3);
      R00 = Hb2[(size_t)(unsigned)j0 * 32 + hl];
      R01 = Hb2[(size_t)(unsigned)j1 * 32 + hl];
      R02 = Hb2[(size_t)(unsigned)j2 * 32 + hl];
      R03 = Hb2[(size_t)(unsigned)j3 * 32 + hl];
      LOADPK(1, j0, j1, j2, j3, wB0, wB1, wB2, wB3);
      R10 = Hb2[(size_t)(unsigned)j0 * 32 + hl];
      R11 = Hb2[(size_t)(unsigned)j1 * 32 + hl];
      R12 = Hb2[(size_t)(unsigned)j2 * 32 + hl];
      R13 = Hb2[(size_t)(unsigned)j3 * 32 + hl];
      LOADPK(2, j0, j1, j2, j3, wA0, wA1, wA2, wA3);
      for (int g = 0; g < Gmax; ++g) {
        uint2 R20, R21, R22, R23;
        if (g + 2 < Gmax) {
          R20 = Hb2[(size_t)(unsigned)j0 * 32 + hl];
          R21 = Hb2[(size_t)(unsigned)j1 * 32 + hl];
          R22 = Hb2[(size_t)(unsigned)j2 * 32 + hl];
          R23 = Hb2[(size_t)(unsigned)j3 * 32 + hl];
        }
        int k0, k1, k2, k3;
        float wN0, wN1, wN2, wN3;
        if (g + 3 < Gmax) {
          LOADPK(g + 3, k0, k1, k2, k3, wN0, wN1, wN2, wN3);
        } else {
          k0 = k1 = k2 = k3 = 0;
          wN0 = wN1 = wN2 = wN3 = INVALW;
        }
        float f0, f1, f2, f3;
        if (GAT) {
          f0 = __expf(leaky(wC0 + edi)); f1 = __expf(leaky(wC1 + edi));
          f2 = __expf(leaky(wC2 + edi)); f3 = __expf(leaky(wC3 + edi));
        } else {
          f0 = wC0; f1 = wC1; f2 = wC2; f3 = wC3;
        }
        __builtin_amdgcn_s_setprio(1);
        c0 = fmaf(blo(R00.x), f0, c0); c1 = fmaf(bhi(R00.x), f0, c1);
        c2 = fmaf(blo(R00.y), f0, c2); c3 = fmaf(bhi(R00.y), f0, c3);
        c0 = fmaf(blo(R01.x), f1, c0); c1 = fmaf(bhi(R01.x), f1, c1);
        c2 = fmaf(blo(R01.y), f1, c2); c3 = fmaf(bhi(R01.y), f1, c3);
        c0 = fmaf(blo(R02.x), f2, c0); c1 = fmaf(bhi(R02.x), f2, c1);
        c2 = fmaf(blo(R02.y), f2, c2); c3 = fmaf(bhi(R02.y), f2, c3);
        c0 = fmaf(blo(R03.x), f3, c0); c1 = fmaf(bhi(R03.x), f3, c1);
        c2 = fmaf(blo(R03.y), f3, c2); c3 = fmaf(bhi(R03.y), f3, c3);
        __builtin_amdgcn_s_setprio(0);
        R00 = R10; R01 = R11; R02 = R12; R03 = R13;
        R10 = R20; R11 = R21; R12 = R22; R13 = R23;
        wC0 = wB0; wC1 = wB1; wC2 = wB2; wC3 = wB3;
        wB0 = wA0; wB1 = wA1; wB2 = wA2; wB3 = wA3;
        wA0 = wN0; wA1 = wN1; wA2 = wN2; wA3 = wN3;
        j0 = k0; j1 = k1; j2 = k2; j3 = k3;
      }
    }
    if (GAT) { c0 *= fscale; c1 *= fscale; c2 *= fscale; c3 *= fscale; }
    ((uint2*)aggb)[(size_t)n * 32 + hl] = make_uint2(packh2(c0, c1), packh2(c2, c3));
    s0 += c0; s1 += c1; s2 += c2; s3 += c3;
    q0 += c0 * c0; q1 += c1 * c1; q2 += c2 * c2; q3 += c3 * c3;
  }
#undef LOADPK
  s0 += __shfl_xor(s0, 32); s1 += __shfl_xor(s1, 32);
  s2 += __shfl_xor(s2, 32); s3 += __shfl_xor(s3, 32);
  q0 += __shfl_xor(q0, 32); q1 += __shfl_xor(q1, 32);
  q2 += __shfl_xor(q2, 32); q3 += __shfl_xor(q3, 32);
  __shared__ float red[4][128];
  int w = tid >> 6;
  if (half == 0) {
    red[w][4 * hl + 0] = s0; red[w][4 * hl + 1] = s1;
    red[w][4 * hl + 2] = s2; red[w][4 * hl + 3] = s3;
  }
  __syncthreads();
  if (w == 0) {
    float a = red[0][2 * lane] + red[1][2 * lane] + red[2][2 * lane] + red[3][2 * lane];
    float b = red[0][2 * lane + 1] + red[1][2 * lane + 1] + red[2][2 * lane + 1] + red[3][2 * lane + 1];
    atomicAdd(&stats[2 * lane], a);
    atomicAdd(&stats[2 * lane + 1], b);
  }
  __syncthreads();
  if (half == 0) {
    red[w][4 * hl + 0] = q0; red[w][4 * hl + 1] = q1;
    red[w][4 * hl + 2] = q2; red[w][4 * hl + 3] = q3;
  }
  __syncthreads();
  if (w == 0) {
    float a = red[0][2 * lane] + red[1][2 * lane] + red[2][2 * lane] + red[3][2 * lane];
    float b = red[0][2 * lane + 1] + red[1][2 * lane + 1] + red[2][2 * lane + 1] + red[3][2 * lane + 1];
    atomicAdd(&stats[128 + 2 * lane], a);
    atomicAdd(&stats[128 + 2 * lane + 1], b);
  }
}

// ---------------- es/ed for GAT ----------------
__global__ __launch_bounds__(256) void compute_esed(const uint32_t* __restrict__ Hb,
                                                    const float* __restrict__ asrc,
                                                    const float* __restrict__ adst,
                                                    float* __restrict__ es, float* __restrict__ ed) {
  int lane = threadIdx.x & 63;
  int gwave = (blockIdx.x * 256 + threadIdx.x) >> 6;
  if (gwave >= N_NODES) return;
  float2 av = ((const float2*)asrc)[lane];
  float2 dv = ((const float2*)adst)[lane];
  uint32_t hv = Hb[(size_t)gwave * 64 + lane];
  float hx = blo(hv), hy = bhi(hv);
  float e_s = hx * av.x + hy * av.y;
  float e_d = hx * dv.x + hy * dv.y;
  for (int off = 32; off; off >>= 1) {
    e_s += __shfl_down(e_s, off);
    e_d += __shfl_down(e_d, off);
  }
  if (lane == 0) { es[gwave] = e_s; ed[gwave] = e_d; }
}

// overwrite pack.y: pads (y==0, only possible for pad slots) -> -1e30 sentinel; else es[src]
__global__ void gat_pack_kernel(int2* __restrict__ sw, const float* __restrict__ es) {
  int e = blockIdx.x * 256 + threadIdx.x;
  if (e < CSR_CAP) {
    int2 v = sw[e];
    v.y = (v.y == 0) ? __float_as_int(-1e30f) : __float_as_int(es[v.x]);
    sw[e] = v;
  }
}

// ---------------- pooling with fused BN+ReLU+residual of last layer; bf16 out ----------------
__global__ void graph_starts(const int* __restrict__ batch, int* __restrict__ gstart) {
  int n = blockIdx.x * 256 + threadIdx.x;
  if (n >= N_NODES) return;
  int b = batch[n];
  int bp = (n == 0) ? -1 : batch[n - 1];
  for (int g = bp + 1; g <= b; ++g) gstart[g] = n;
  if (n == N_NODES - 1) {
    for (int g = b + 1; g <= BG; ++g) gstart[g] = N_NODES;
  }
}

__global__ __launch_bounds__(256) void pool_bn(const uint32_t* __restrict__ aggb,
                                               const uint32_t* __restrict__ xb,
                                               const float* __restrict__ stats,
                                               const float* __restrict__ gamma,
                                               const float* __restrict__ beta,
                                               const int* __restrict__ gstart,
                                               uint32_t* __restrict__ pooledb) {
  int g = blockIdx.x;
  int c = threadIdx.x & 127;
  int half = threadIdx.x >> 7;
  const float n_inv = 1.f / (float)N_NODES;
  float m = stats[c] * n_inv;
  float v = stats[128 + c] * n_inv - m * m;
  float sc = gamma[c] * rsqrtf(v + BN_EPS);
  float bc = beta[c] - m * sc;
  int s = gstart[g], e = gstart[g + 1];
  float acc = 0.f;
  for (int n = s + half; n < e; n += 2) {
    uint32_t aw = aggb[(size_t)n * 64 + (c >> 1)];
    float a = (c & 1) ? hhi(aw) : hlo(aw);
    uint32_t u = xb[(size_t)n * 64 + (c >> 1)];
    float xo = (c & 1) ? bhi(u) : blo(u);
    acc += fmaxf(fmaf(a, sc, bc), 0.f) + xo;
  }
  __shared__ float red[256];
  __shared__ float fin[128];
  red[threadIdx.x] = acc;
  __syncthreads();
  if (half == 0) {
    float vsum = red[c] + red[128 + c];
    int cnt = e - s;
    fin[c] = vsum / fmaxf((float)cnt, 1.f);
  }
  __syncthreads();
  if (half == 0 && !(c & 1))
    pooledb[(size_t)g * 64 + (c >> 1)] = pack2(fin[c], fin[c + 1]);
}

// ---------------- host launch ----------------
extern "C" void kernel_launch(void* const* d_in, const int* in_sizes, int n_in,
                              void* d_out, int out_size, void* d_ws, size_t ws_size,
                              hipStream_t stream) {
  const float* x_in  = (const float*)d_in[0];
  const int*   eidx  = (const int*)d_in[1];
  const int*   batch = (const int*)d_in[2];
  const float* W1 = (const float*)d_in[3];
  const float* g1 = (const float*)d_in[5];
  const float* be1 = (const float*)d_in[6];
  const float* W2 = (const float*)d_in[7];
  const float* g2 = (const float*)d_in[9];
  const float* be2 = (const float*)d_in[10];
  const float* W3 = (const float*)d_in[11];
  const float* g3 = (const float*)d_in[13];
  const float* be3 = (const float*)d_in[14];
  const float* Wa = (const float*)d_in[15];
  const float* asrc = (const float*)d_in[16];
  const float* adst = (const float*)d_in[17];
  const float* ga = (const float*)d_in[19];
  const float* bea = (const float*)d_in[20];
  const float* Wh1 = (const float*)d_in[21];
  const float* bh1 = (const float*)d_in[22];
  const float* Wm0 = (const float*)d_in[23];
  const float* bm0 = (const float*)d_in[24];
  const float* Wm1 = (const float*)d_in[25];
  const float* bm1 = (const float*)d_in[26];
  const float* Wo = (const float*)d_in[27];
  const float* bo = (const float*)d_in[28];

  const int* src = eidx;
  const int* dst = eidx + N_EDGES;

  char* p = (char*)d_ws;
  auto alloc = [&](size_t bytes) {
    char* r = p;
    p += (bytes + 255) & ~(size_t)255;
    return r;
  };
  uint32_t* Hb     = (uint32_t*)alloc((size_t)N_NODES * 64 * 4);
  uint32_t* xb     = (uint32_t*)alloc((size_t)N_NODES * 64 * 4);
  uint32_t* aggb   = (uint32_t*)alloc((size_t)N_NODES * 64 * 4);   // fp16 pairs
  int2*  csr_sw    = (int2*)alloc((size_t)CSR_CAP * 8);
  int*   rowstart  = (int*)alloc((size_t)(N_NODES + 1) * 4);
  int*   indeg     = (int*)alloc((size_t)2 * N_NODES * 4);
  int*   cursor    = indeg + N_NODES;
  float* dinv      = (float*)alloc((size_t)N_NODES * 4);
  float* es        = (float*)alloc((size_t)N_NODES * 4);
  float* ed        = (float*)alloc((size_t)N_NODES * 4);
  int*   chunksum  = (int*)alloc(128 * 4);
  float* stats     = (float*)alloc(4 * 256 * 4);
  int*   gstart    = (int*)alloc((BG + 1) * 4);
  uint32_t* pooledb = (uint32_t*)alloc((size_t)BG * 64 * 4);
  uint32_t* m1b    = (uint32_t*)alloc((size_t)BG * (NHID / 2) * 4);
  uint32_t* m2b    = (uint32_t*)alloc((size_t)BG * (NHID / 2) * 4);
  unsigned short* Wp1 = (unsigned short*)alloc(2048 * 8 * 2);
  unsigned short* Wp2 = (unsigned short*)alloc(2048 * 8 * 2);
  unsigned short* Wp3 = (unsigned short*)alloc(2048 * 8 * 2);
  unsigned short* Wp4 = (unsigned short*)alloc(2048 * 8 * 2);
  unsigned short* P1 = (unsigned short*)alloc((size_t)8192 * 8 * 2);
  unsigned short* P2 = (unsigned short*)alloc((size_t)32768 * 8 * 2);
  unsigned short* P3 = (unsigned short*)alloc((size_t)32768 * 8 * 2);
  unsigned short* P4 = (unsigned short*)alloc((size_t)16384 * 8 * 2);

  hipMemsetAsync(indeg, 0, (size_t)2 * N_NODES * 4, stream);
  hipMemsetAsync(stats, 0, 4 * 256 * 4, stream);
  hipMemsetAsync(csr_sw, 0, (size_t)CSR_CAP * 8, stream);

  // CSR build (padded rows)
  hist_kernel<<<(N_EDGES + 255) / 256, 256, 0, stream>>>(dst, indeg);
  scan_chunks<<<98, 256, 0, stream>>>(indeg, rowstart, chunksum);
  scan_sums<<<1, 128, 0, stream>>>(chunksum, 98, rowstart + N_NODES);
  scan_add_dinv<<<(N_NODES + 255) / 256, 256, 0, stream>>>(rowstart, chunksum, indeg, dinv);
  scatter_edges<<<(N_EDGES + 255) / 256, 256, 0, stream>>>(src, dst, rowstart, cursor, dinv, csr_sw);

  // prep: cast x + pack conv weights + pack MLP weights
  prep_kernel<<<25000 + 32, 256, 0, stream>>>((const float2*)x_in, xb, W1, W2, W3, Wa,
                                              Wp1, Wp2, Wp3, Wp4);
  pack_mlp<<<352, 256, 0, stream>>>(Wh1, Wm0, Wm1, Wo, P1, P2, P3, P4);

  const int gemm_blocks_m = (N_NODES + 127) / 128;  // 782
  const int AGG_BLOCKS = 2048;

  // layer 1
  gemm_mfma<0><<<gemm_blocks_m, 256, 0, stream>>>(xb, nullptr, nullptr, nullptr, nullptr,
                                                  Wp1, Hb, N_NODES);
  agg_kernel<0><<<AGG_BLOCKS, 256, 0, stream>>>((const uint2*)Hb, rowstart, csr_sw, dinv,
                                                indeg, nullptr, nullptr, aggb, stats + 0 * 256);
  // layer 2 (fuse BN1)
  gemm_mfma<1><<<gemm_blocks_m, 256, 0, stream>>>(xb, aggb, stats + 0 * 256, g1, be1,
                                                  Wp2, Hb, N_NODES);
  agg_kernel<0><<<AGG_BLOCKS, 256, 0, stream>>>((const uint2*)Hb, rowstart, csr_sw, dinv,
                                                indeg, nullptr, nullptr, aggb, stats + 1 * 256);
  // layer 3 (fuse BN2)
  gemm_mfma<1><<<gemm_blocks_m, 256, 0, stream>>>(xb, aggb, stats + 1 * 256, g2, be2,
                                                  Wp3, Hb, N_NODES);
  agg_kernel<0><<<AGG_BLOCKS, 256, 0, stream>>>((const uint2*)Hb, rowstart, csr_sw, dinv,
                                                indeg, nullptr, nullptr, aggb, stats + 2 * 256);
  // layer 4 = GAT (fuse BN3)
  gemm_mfma<1><<<gemm_blocks_m, 256, 0, stream>>>(xb, aggb, stats + 2 * 256, g3, be3,
                                                  Wp4, Hb, N_NODES);
  compute_esed<<<(N_NODES + 3) / 4, 256, 0, stream>>>(Hb, asrc, adst, es, ed);
  gat_pack_kernel<<<(CSR_CAP + 255) / 256, 256, 0, stream>>>(csr_sw, es);
  agg_kernel<1><<<AGG_BLOCKS, 256, 0, stream>>>((const uint2*)Hb, rowstart, csr_sw, nullptr,
                                                indeg, es, ed, aggb, stats + 3 * 256);

  // pooling (fuses BN4), bf16 out
  graph_starts<<<(N_NODES + 255) / 256, 256, 0, stream>>>(batch, gstart);
  pool_bn<<<BG, 256, 0, stream>>>(aggb, xb, stats + 3 * 256, ga, bea, gstart, pooledb);

  // MLP head (MFMA bf16)
  gemm_mlp<1, 0><<<dim3(4, 4), 256, 0, stream>>>(pooledb, P1, bh1, m1b, BG, CCH, NHID);
  gemm_mlp<1, 0><<<dim3(4, 4), 256, 0, stream>>>(m1b, P2, bm0, m2b, BG, NHID, NHID);
  gemm_mlp<1, 0><<<dim3(4, 4), 256, 0, stream>>>(m2b, P3, bm1, m1b, BG, NHID, NHID);
  gemm_mlp<0, 1><<<dim3(4, 2), 256, 0, stream>>>(m1b, P4, bo, d_out, BG, NHID, NOUT);
}